// Round 2
// baseline (840.332 us; speedup 1.0000x reference)
//
#include <hip/hip_runtime.h>
#include <stdint.h>

// ---------------------------------------------------------------------------
// B=256, H=W=14, HW=196, TS=0.03, TC=0.07, TP_K=19, TN_K=98
// Conv inputs: padded 16x16 cell grid per image (1-cell zero halo):
// cell = b*256 + (h+1)*16 + (w+1). Conv 3x3 = 9 cell-row shifts d=dh*16+dw.
// convtap6_k: block = ONE image (M padded 196->224 rows) x 128 N. The A
// window per kc is EXACTLY the image's 256 cell rows (36.9 KB) — covers all
// 9 taps incl. halo with no clamping, no cross-image span. acc 7x4/wave.
// M-tiling: each 16x16 MFMA tile = a 2x8 PIXEL BLOCK of the padded grid
// (tq -> dh=tq>>3, dw=tq&7; mi -> h-pair 1+2*mi; wm -> w-half) so the A-read
// bank-start residue 4*((tq&7)+quad) is uniform per quarter-wave, all taps.
// B PATH (R1): weights live in per-wave REGISTERS, not LDS. wb1/wb2 are
// pre-packed in MFMA-fragment order — 16B per lane, 1KB fully-coalesced span
// per (n-group, K-half): off16 = (t*KC+kc)*4096 + g*128 + h*64 + lane.
// Each step does 8 global_load_dwordx4 (L2-resident ~4.7MB weight set)
// instead of global_load_lds staging + 8 ds_reads. This removes the per-step
// vmcnt(0)+barrier drain entirely: barriers remain ONLY at kc boundaries
// (A window restage). LDS/block drops 73.7KB -> 36.9KB.
// Grid 256x4 at 2 blocks/CU -> exactly 4 slots/CU, no tail quantization.
// NOTE: workspace regions are reused; size each by the MAX of its occupants.
// ---------------------------------------------------------------------------

typedef __attribute__((ext_vector_type(8))) short bf16x8;
typedef __attribute__((ext_vector_type(4))) float f32x4;

__device__ __forceinline__ unsigned short f2bf(float x) {
  unsigned u = __float_as_uint(x);
  unsigned r = u + 0x7FFFu + ((u >> 16) & 1u);  // RNE, no NaNs here
  return (unsigned short)(r >> 16);
}
__device__ __forceinline__ float bf2f(unsigned short h) {
  return __uint_as_float(((unsigned)h) << 16);
}

typedef const __attribute__((address_space(1))) void* gptr1_t;
typedef __attribute__((address_space(3))) void* lptr3_t;
__device__ __forceinline__ void gload_lds16(const void* g, void* l) {
  __builtin_amdgcn_global_load_lds((gptr1_t)g, (lptr3_t)l, 16, 0, 0);
}

__device__ __forceinline__ float waveSum(float v) {
#pragma unroll
  for (int m = 1; m < 64; m <<= 1) v += __shfl_xor(v, m, 64);
  return v;
}
__device__ __forceinline__ float waveMax(float v) {
#pragma unroll
  for (int m = 1; m < 64; m <<= 1) v = fmaxf(v, __shfl_xor(v, m, 64));
  return v;
}
template <int NW>
__device__ __forceinline__ float blockSum(float v) {
  __shared__ float sh[NW];
  v = waveSum(v);
  int wv = threadIdx.x >> 6, ln = threadIdx.x & 63;
  if (ln == 0) sh[wv] = v;
  __syncthreads();
  float r = 0.f;
#pragma unroll
  for (int w = 0; w < NW; ++w) r += sh[w];
  __syncthreads();
  return r;
}
template <int NW>
__device__ __forceinline__ float blockMax(float v) {
  __shared__ float sh[NW];
  v = waveMax(v);
  int wv = threadIdx.x >> 6, ln = threadIdx.x & 63;
  if (ln == 0) sh[wv] = v;
  __syncthreads();
  float r = -3.4e38f;
#pragma unroll
  for (int w = 0; w < NW; ++w) r = fmaxf(r, sh[w]);
  __syncthreads();
  return r;
}

#define RA 65536  // rows per k-slice of conv input buffers

// ---------------------------------------------------------------------------
// convtap6_k: one image per block-x. C[p,n] = sum_t sum_k A[cell(p)+d_t,k]B[t,n,k]
// 256 thr, 4 waves (wm in {0,1}: w-half, wn in {0,1}: 64 cols), acc 7x4 of
// 16x16x32 bf16 MFMA. A: [kc][RA][72] shorts (LDS window 256x72 = 36.9 KB).
// B: fragment-packed [t][kc][g(32)][h(2)][lane(64)][8] shorts, reg-loaded.
// EPI 0: relu -> x1b (cell rows, k-major slices). EPI 1: bf16 -> fv compact.
// ---------------------------------------------------------------------------
template <int KC, int EPI>
__global__ __launch_bounds__(256, 2) void convtap6_k(
    const unsigned short* __restrict__ A, const unsigned short* __restrict__ Bw,
    unsigned short* __restrict__ C) {
  __shared__ __align__(16) short Ah[256 * 72];
  const int tid = threadIdx.x;
  const int wave = tid >> 6, lane = tid & 63;
  const int wm = wave >> 1, wn = wave & 1;
  const int quad = lane >> 4, tq = lane & 15;
  const int img = blockIdx.x, n0 = blockIdx.y * 128;

  // A-row per MFMA tile: tile = 2x8 pixel block; lane tq -> (dh, dw).
  int pab[7];
  {
    const int dh = tq >> 3;
    int wq = wm * 8 + (tq & 7);          // w' in 0..15
    if (wq == 0) wq = 8;                 // dead col -> mirrored valid col,
    else if (wq == 15) wq = 7;           // same bank residue, taps in-bounds
#pragma unroll
    for (int mi = 0; mi < 7; ++mi) {
      int pr = (1 + 2 * mi + dh) * 16 + wq;  // h' in 1..14
      pab[mi] = pr * 72 + quad * 8;
    }
  }
  // B fragment base (16B units): (t*KC+kc)*4096 + g*128 + h*64 + lane
  const int gb = (n0 >> 4) + wn * 4;

  const char* Ab = (const char*)A;
  const int l16 = lane * 16;

  f32x4 acc[7][4];
#pragma unroll
  for (int mi = 0; mi < 7; ++mi)
#pragma unroll
    for (int ni = 0; ni < 4; ++ni) {
      f32x4 z = {0.f, 0.f, 0.f, 0.f};
      acc[mi][ni] = z;
    }

  auto stageA = [&](int kc) {
    size_t s0 = ((size_t)kc * RA + img * 256) * 144;
#pragma unroll
    for (int i = 0; i < 9; ++i) {
      int c = wave + i * 4;  // 36 chunks of 1024 B
      gload_lds16(Ab + s0 + (size_t)c * 1024 + l16, (char*)Ah + c * 1024);
    }
  };

  stageA(0);
  __syncthreads();

  const int NS = KC * 9;
#pragma unroll 1
  for (int s = 0; s < NS; ++s) {
    int kc = s / 9, t = s - kc * 9;
    const int b16 = (t * KC + kc) * 4096 + gb * 128 + lane;
    // h=0 fragments: issue global loads (L2-resident), then A ds_reads
    bf16x8 bw0[4];
#pragma unroll
    for (int ni = 0; ni < 4; ++ni)
      bw0[ni] = *(const bf16x8*)&Bw[(size_t)(b16 + ni * 128) * 8];
    const int aoff = (((t / 3) - 1) * 16 + (t % 3) - 1) * 72;
    bf16x8 af0[7];
#pragma unroll
    for (int mi = 0; mi < 7; ++mi)
      af0[mi] = *(const bf16x8*)&Ah[pab[mi] + aoff];
    // h=1 fragments: issue now; latency hidden under the h=0 MFMA cluster
    bf16x8 bw1[4];
#pragma unroll
    for (int ni = 0; ni < 4; ++ni)
      bw1[ni] = *(const bf16x8*)&Bw[(size_t)(b16 + ni * 128 + 64) * 8];
#pragma unroll
    for (int mi = 0; mi < 7; ++mi)
#pragma unroll
      for (int ni = 0; ni < 4; ++ni)
        acc[mi][ni] = __builtin_amdgcn_mfma_f32_16x16x32_bf16(
            af0[mi], bw0[ni], acc[mi][ni], 0, 0, 0);
    bf16x8 af1[7];
#pragma unroll
    for (int mi = 0; mi < 7; ++mi)
      af1[mi] = *(const bf16x8*)&Ah[pab[mi] + aoff + 32];
#pragma unroll
    for (int mi = 0; mi < 7; ++mi)
#pragma unroll
      for (int ni = 0; ni < 4; ++ni)
        acc[mi][ni] = __builtin_amdgcn_mfma_f32_16x16x32_bf16(
            af1[mi], bw1[ni], acc[mi][ni], 0, 0, 0);
    if (t == 8 && kc + 1 < KC) {
      __syncthreads();
      stageA(kc + 1);
      __syncthreads();
    }
  }

#pragma unroll
  for (int mi = 0; mi < 7; ++mi) {
#pragma unroll
    for (int r = 0; r < 4; ++r) {
      int idx = quad * 4 + r;            // M-row within tile, 0..15
      int wv = wm * 8 + (idx & 7);       // w' in 0..15
      if (wv == 0 || wv == 15) continue;  // dead column (halo)
      int hh = 1 + 2 * mi + (idx >> 3);  // h' in 1..14
      if (EPI == 0) {
        int cell = img * 256 + hh * 16 + wv;
        int slice = (n0 >> 6) + wn;
        size_t ob = ((size_t)slice * RA + cell) * 72 + tq;
#pragma unroll
        for (int ni = 0; ni < 4; ++ni)
          C[ob + ni * 16] = f2bf(fmaxf(acc[mi][ni][r], 0.f));
      } else {
        int p = (hh - 1) * 14 + (wv - 1);
        size_t ob = (size_t)(img * 196 + p) * 512 + n0 + wn * 64 + tq;
#pragma unroll
        for (int ni = 0; ni < 4; ++ni)
          C[ob + ni * 16] = f2bf(acc[mi][ni][r]);
      }
    }
  }
}

// ---------------------------------------------------------------------------
// gemm1_k: C[m,n] = sum_k A[m,k]*B[n,k]; 128x128 tile, 4 waves, BK=64,
// XOR-swizzled LDS. EPI: 0 relu->bf16, 2 f32, 3 f32 * rs[m] (row scale).
// ---------------------------------------------------------------------------
template <int K, int NLD, int EPI>
__global__ __launch_bounds__(256, 2) void gemm1_k(
    const unsigned short* __restrict__ A, const unsigned short* __restrict__ Bw,
    void* __restrict__ C, const float* __restrict__ rs) {
  __shared__ short As[128 * 64];
  __shared__ short Bs[128 * 64];
  const int tid = threadIdx.x;
  const int wave = tid >> 6, lane = tid & 63;
  const int m0 = blockIdx.x * 128, n0 = blockIdx.y * 128;
  const int rr8 = lane >> 3, seg = lane & 7, gseg = seg ^ rr8;
  const int wm = wave >> 1, wn = wave & 1;
  const int quad = lane >> 4, tq = lane & 15;

  size_t asrc[4], bsrc[4];
#pragma unroll
  for (int i8 = 0; i8 < 4; ++i8) {
    int rloc = wave * 32 + i8 * 8 + rr8;
    asrc[i8] = (size_t)(m0 + rloc) * K + gseg * 8;
    bsrc[i8] = (size_t)(n0 + rloc) * K + gseg * 8;
  }

  f32x4 acc[4][4];
#pragma unroll
  for (int mi = 0; mi < 4; ++mi)
#pragma unroll
    for (int ni = 0; ni < 4; ++ni) {
      f32x4 z = {0.f, 0.f, 0.f, 0.f};
      acc[mi][ni] = z;
    }

#pragma unroll 1
  for (int kc2 = 0; kc2 < K / 64; ++kc2) {
    int kb = kc2 * 64;
    __syncthreads();
#pragma unroll
    for (int i8 = 0; i8 < 4; ++i8) {
      gload_lds16(A + asrc[i8] + kb, &As[(wave * 32 + i8 * 8) * 64]);
      gload_lds16(Bw + bsrc[i8] + kb, &Bs[(wave * 32 + i8 * 8) * 64]);
    }
    __syncthreads();
#pragma unroll
    for (int h = 0; h < 2; ++h) {
      bf16x8 af[4], bfr[4];
#pragma unroll
      for (int mi = 0; mi < 4; ++mi) {
        int row = wm * 64 + mi * 16 + tq;
        af[mi] = *(const bf16x8*)&As[row * 64 +
                                     ((((h << 2) | quad) ^ (row & 7)) << 3)];
      }
#pragma unroll
      for (int ni = 0; ni < 4; ++ni) {
        int row = wn * 64 + ni * 16 + tq;
        bfr[ni] = *(const bf16x8*)&Bs[row * 64 +
                                      ((((h << 2) | quad) ^ (row & 7)) << 3)];
      }
#pragma unroll
      for (int mi = 0; mi < 4; ++mi)
#pragma unroll
        for (int ni = 0; ni < 4; ++ni)
          acc[mi][ni] = __builtin_amdgcn_mfma_f32_16x16x32_bf16(
              af[mi], bfr[ni], acc[mi][ni], 0, 0, 0);
    }
  }

#pragma unroll
  for (int mi = 0; mi < 4; ++mi) {
#pragma unroll
    for (int r = 0; r < 4; ++r) {
      int m = m0 + wm * 64 + mi * 16 + quad * 4 + r;
      float sc = (EPI == 3) ? rs[m] : 1.f;
      size_t obase = (size_t)m * NLD + n0 + wn * 64 + tq;
#pragma unroll
      for (int ni = 0; ni < 4; ++ni) {
        float v = acc[mi][ni][r];
        size_t idx = obase + ni * 16;
        if (EPI == 0)
          ((unsigned short*)C)[idx] = f2bf(fmaxf(v, 0.f));
        else if (EPI == 2)
          ((float*)C)[idx] = v;
        else
          ((float*)C)[idx] = v * sc;
      }
    }
  }
}

// Xm = (iv+eps).fa^T and Vm = indn.indn^T in one dispatch (blockIdx.z picks)
__global__ __launch_bounds__(256, 2) void gemm_xv_k(
    const unsigned short* __restrict__ ivpb, const unsigned short* __restrict__ fab,
    const unsigned short* __restrict__ indnb, float* __restrict__ Xm,
    float* __restrict__ Vm) {
  const unsigned short* A = blockIdx.z ? indnb : ivpb;
  const unsigned short* Bw = blockIdx.z ? indnb : fab;
  float* C = blockIdx.z ? Vm : Xm;
  __shared__ short As[128 * 64];
  __shared__ short Bs[128 * 64];
  const int tid = threadIdx.x;
  const int wave = tid >> 6, lane = tid & 63;
  const int m0 = blockIdx.x * 128, n0 = blockIdx.y * 128;
  const int rr8 = lane >> 3, seg = lane & 7, gseg = seg ^ rr8;
  const int wm = wave >> 1, wn = wave & 1;
  const int quad = lane >> 4, tq = lane & 15;
  size_t asrc[4], bsrc[4];
#pragma unroll
  for (int i8 = 0; i8 < 4; ++i8) {
    int rloc = wave * 32 + i8 * 8 + rr8;
    asrc[i8] = (size_t)(m0 + rloc) * 512 + gseg * 8;
    bsrc[i8] = (size_t)(n0 + rloc) * 512 + gseg * 8;
  }
  f32x4 acc[4][4];
#pragma unroll
  for (int mi = 0; mi < 4; ++mi)
#pragma unroll
    for (int ni = 0; ni < 4; ++ni) {
      f32x4 z = {0.f, 0.f, 0.f, 0.f};
      acc[mi][ni] = z;
    }
#pragma unroll 1
  for (int kc2 = 0; kc2 < 8; ++kc2) {
    int kb = kc2 * 64;
    __syncthreads();
#pragma unroll
    for (int i8 = 0; i8 < 4; ++i8) {
      gload_lds16(A + asrc[i8] + kb, &As[(wave * 32 + i8 * 8) * 64]);
      gload_lds16(Bw + bsrc[i8] + kb, &Bs[(wave * 32 + i8 * 8) * 64]);
    }
    __syncthreads();
#pragma unroll
    for (int h = 0; h < 2; ++h) {
      bf16x8 af[4], bfr[4];
#pragma unroll
      for (int mi = 0; mi < 4; ++mi) {
        int row = wm * 64 + mi * 16 + tq;
        af[mi] = *(const bf16x8*)&As[row * 64 +
                                     ((((h << 2) | quad) ^ (row & 7)) << 3)];
      }
#pragma unroll
      for (int ni = 0; ni < 4; ++ni) {
        int row = wn * 64 + ni * 16 + tq;
        bfr[ni] = *(const bf16x8*)&Bs[row * 64 +
                                      ((((h << 2) | quad) ^ (row & 7)) << 3)];
      }
#pragma unroll
      for (int mi = 0; mi < 4; ++mi)
#pragma unroll
        for (int ni = 0; ni < 4; ++ni)
          acc[mi][ni] = __builtin_amdgcn_mfma_f32_16x16x32_bf16(
              af[mi], bfr[ni], acc[mi][ni], 0, 0, 0);
    }
  }
#pragma unroll
  for (int mi = 0; mi < 4; ++mi)
#pragma unroll
    for (int r = 0; r < 4; ++r) {
      int m = m0 + wm * 64 + mi * 16 + quad * 4 + r;
      size_t obase = (size_t)m * 256 + n0 + wn * 64 + tq;
#pragma unroll
      for (int ni = 0; ni < 4; ++ni) C[obase + ni * 16] = acc[mi][ni][r];
    }
}

// --------------------------- prep (fused) ----------------------------------
// ranges: ea/Wf1/Wf2 casts | wb1 build | wb2 build | x1b halo zeroing
// wb layout (R1, fragment-packed): flat index j =
//   (((t*KC+kc)*32 + g)*2 + h)*512 + quad*128 + tq*8 + jj
// value = Wc[n = g*16+tq][cin = kc*64 + h*32 + quad*8 + jj][tap t]
// -> writes are perfectly linear; the conv kernel reads 1KB coalesced spans.
__global__ void prep_all_k(const float* __restrict__ ea,
                           const float* __restrict__ Wf1,
                           const float* __restrict__ Wf2,
                           const float* __restrict__ Wc1,
                           const float* __restrict__ Wc2,
                           unsigned short* __restrict__ eab,
                           unsigned short* __restrict__ wf1b,
                           unsigned short* __restrict__ wf2b,
                           unsigned short* __restrict__ wb1,
                           unsigned short* __restrict__ wb2,
                           unsigned int* __restrict__ x1u) {
  int i = blockIdx.x * 256 + threadIdx.x;
  if (i < 524288) {
    eab[i] = f2bf(ea[i]);
  } else if (i < 1572864) {
    int j = i - 524288;
    wf1b[j] = f2bf(Wf1[j]);
  } else if (i < 1835008) {
    int j = i - 1572864;
    wf2b[j] = f2bf(Wf2[j]);
  } else if (i < 3604480) {
    int j = i - 1835008;  // wb1: 9*6*32768 fragment-packed <- Wc1[n][384][3][3]
    int t = j / (6 * 32768), r = j - t * (6 * 32768);
    int kc = r / 32768, r2 = r - kc * 32768;
    int g = r2 >> 10, h = (r2 >> 9) & 1, quad = (r2 >> 7) & 3;
    int tq = (r2 >> 3) & 15, jj = r2 & 7;
    int n = g * 16 + tq, cin = kc * 64 + h * 32 + quad * 8 + jj;
    wb1[j] = f2bf(Wc1[(n * 384 + cin) * 9 + t]);
  } else if (i < 5963776) {
    int j = i - 3604480;  // wb2: 9*8*32768 fragment-packed <- Wc2[n][512][3][3]
    int t = j / (8 * 32768), r = j - t * (8 * 32768);
    int kc = r / 32768, r2 = r - kc * 32768;
    int g = r2 >> 10, h = (r2 >> 9) & 1, quad = (r2 >> 7) & 3;
    int tq = (r2 >> 3) & 15, jj = r2 & 7;
    int n = g * 16 + tq, cin = kc * 64 + h * 32 + quad * 8 + jj;
    wb2[j] = f2bf(Wc2[(n * 512 + cin) * 9 + t]);
  } else {
    int j = i - 5963776;  // 15360 halo rows x 8 slices x 32 uints
    int hr = j >> 8, u = j & 255;
    int slice = u >> 5, uu = u & 31;
    int b = hr / 60, c = hr - b * 60;
    int cell;
    if (c < 16) cell = c;
    else if (c < 32) cell = 240 + (c - 16);
    else if (c < 46) cell = (c - 31) * 16;
    else cell = (c - 45) * 16 + 15;
    x1u[((size_t)slice * RA + b * 256 + cell) * 36 + uu] = 0u;
  }
}

// ev (256,384,14,14) fp32 -> evb [kc6][RA][72] bf16 (halo cells zero)
__global__ __launch_bounds__(256) void evpad_k(const float* __restrict__ ev,
                                               unsigned short* __restrict__ out) {
  int b = blockIdx.x, ct = blockIdx.y;  // channel tile: c0 = ct*64
  __shared__ float tile[64][197];
  int tid = threadIdx.x;
  const float* src = ev + ((size_t)b * 384 + ct * 64) * 196;
#pragma unroll 1
  for (int it = 0; it < 49; ++it) {
    int idx = it * 256 + tid;
    int c = idx / 196, p = idx - c * 196;
    tile[c][p] = src[idx];
  }
  __syncthreads();
  unsigned short* dst = out + ((size_t)ct * RA + b * 256) * 72;
#pragma unroll 1
  for (int it = 0; it < 64; ++it) {
    int idx = it * 256 + tid;
    int cell = idx >> 6, c = idx & 63;
    int h = (cell >> 4) - 1, w = (cell & 15) - 1;
    float v = ((unsigned)h < 14u && (unsigned)w < 14u) ? tile[c][h * 14 + w]
                                                       : 0.f;
    dst[(size_t)cell * 72 + c] = f2bf(v);
  }
}

// --------------------------- pooling / norms -------------------------------

// fused: masked mean pool + per-pixel inverse norm (rn) + ind normalization
__global__ __launch_bounds__(512) void pool_k(
    const unsigned short* __restrict__ fv, const int* __restrict__ masks,
    unsigned short* __restrict__ indnb, unsigned short* __restrict__ ivpb,
    float* __restrict__ Pi, float* __restrict__ rn) {
  int b = blockIdx.x;
  int w = threadIdx.x >> 6, lane = threadIdx.x & 63;
  __shared__ float red[8][512];
  __shared__ float msh[8];
  float acc[8] = {0.f, 0.f, 0.f, 0.f, 0.f, 0.f, 0.f, 0.f};
  float msum = 0.f;
  for (int p = w; p < 196; p += 8) {
    float m = (float)masks[b * 196 + p];
    msum += m;
    uint4 d = *(const uint4*)(fv + (size_t)(b * 196 + p) * 512 + lane * 8);
    const unsigned short* hp = (const unsigned short*)&d;
    float ss = 0.f;
#pragma unroll
    for (int k = 0; k < 8; ++k) {
      float x = bf2f(hp[k]);
      ss += x * x;
      acc[k] += m * x;
    }
    ss = waveSum(ss);
    if (lane == 0) rn[b * 196 + p] = 1.f / fmaxf(sqrtf(ss), 1e-12f);
  }
#pragma unroll
  for (int k = 0; k < 8; ++k) red[w][lane * 8 + k] = acc[k];
  if (lane == 0) msh[w] = msum;
  __syncthreads();
  int tid = threadIdx.x;
  float s = 0.f, mtot = 0.f;
#pragma unroll
  for (int ww = 0; ww < 8; ++ww) {
    s += red[ww][tid];
    mtot += msh[ww];
  }
  float v = s / mtot;  // indv[b, tid]
  float ss2 = blockSum<8>(v * v);
  float sc = 1.f / fmaxf(sqrtf(ss2), 1e-12f);
  indnb[b * 512 + tid] = f2bf(v * sc);
  float ve = v + 1e-6f;
  ivpb[b * 512 + tid] = f2bf(ve);
  float p2 = blockSum<8>(ve * ve);
  if (tid == 0) Pi[b] = p2;
}

// fa fp32 -> bf16 + Qj = ||fa_j||^2
__global__ __launch_bounds__(512) void fanorm_k(const float* __restrict__ fa,
                                                unsigned short* __restrict__ fab,
                                                float* __restrict__ Qj) {
  int b = blockIdx.x, tid = threadIdx.x;
  float v = fa[b * 512 + tid];
  fab[b * 512 + tid] = f2bf(v);
  float q = blockSum<8>(v * v);
  if (tid == 0) Qj[b] = q;
}

// ------------------------------ SP / SN ------------------------------------

__device__ __forceinline__ float radix_kth(unsigned k0, unsigned k1, unsigned k2,
                                           unsigned k3, int k) {
  unsigned prefix = 0;
  int kk = k;
#pragma unroll 1
  for (int bit = 31; bit >= 14; --bit) {  // 18 steps; thr err ~2^-9 rel, ok
    unsigned thi = (prefix >> bit) | 1u;
    int c = __popcll(__ballot((k0 >> bit) == thi)) +
            __popcll(__ballot((k1 >> bit) == thi)) +
            __popcll(__ballot((k2 >> bit) == thi)) +
            __popcll(__ballot((k3 >> bit) == thi));
    if (kk <= c)
      prefix |= (1u << bit);
    else
      kk -= c;
  }
  unsigned u = (prefix & 0x80000000u) ? (prefix ^ 0x80000000u) : ~prefix;
  return __uint_as_float(u);
}
__device__ __forceinline__ unsigned sortkey(float x) {
  unsigned u = __float_as_uint(x);
  return u ^ (((int)u >> 31) | 0x80000000u);
}

__global__ __launch_bounds__(256) void spsn_k(const float* __restrict__ Sij,
                                              float* __restrict__ SP,
                                              float* __restrict__ SN) {
  int i = blockIdx.x, jg = blockIdx.y;
  int tid = threadIdx.x, wave = tid >> 6, lane = tid & 63;
  __shared__ float tile[196 * 65];
#pragma unroll 1
  for (int it = 0; it < 49; ++it) {
    int lin = it * 256 + tid;
    int p = lin >> 6, j = lin & 63;
    tile[p * 65 + j] = Sij[(size_t)(i * 196 + p) * 256 + jg * 64 + j];
  }
  __syncthreads();
#pragma unroll 1
  for (int jj = 0; jj < 16; ++jj) {
    int j = jj * 4 + wave;
    float v0 = tile[lane * 65 + j];
    float v1 = tile[(lane + 64) * 65 + j];
    float v2 = tile[(lane + 128) * 65 + j];
    bool val3 = lane < 4;
    float v3 = val3 ? tile[(lane + 192) * 65 + j] : 0.f;
    unsigned k0 = sortkey(v0), k1 = sortkey(v1), k2 = sortkey(v2);
    unsigned k3 = val3 ? sortkey(v3) : 0u;
    float thrP = radix_kth(k0, k1, k2, k3, 19);
    float thrN = radix_kth(k0, k1, k2, k3, 99);
    float spn = 0.f, spd = 0.f, snn = 0.f, snd = 0.f;
    const float invTS = 1.f / 0.03f;
#pragma unroll
    for (int q = 0; q < 4; ++q) {
      float v = (q == 0) ? v0 : (q == 1) ? v1 : (q == 2) ? v2 : v3;
      bool ok = (q < 3) || val3;
      if (ok) {
        float mp = 1.f / (1.f + __expf((thrP - v) * invTS));
        float mn = 1.f / (1.f + __expf((v - thrN) * invTS));
        spn += v * mp;
        spd += mp;
        snn += v * mn;
        snd += mn;
      }
    }
    spn = waveSum(spn); spd = waveSum(spd);
    snn = waveSum(snn); snd = waveSum(snd);
    if (lane == 0) {
      SP[i * 256 + jg * 64 + j] = spn / spd;
      SN[i * 256 + jg * 64 + j] = snn / snd;
    }
  }
}

__global__ __launch_bounds__(256) void loss12_k(const float* __restrict__ SP,
                                                const float* __restrict__ SN,
                                                float* __restrict__ out) {
  int r = blockIdx.x;
  int i = r & 255;
  bool col = r >= 256;
  int tid = threadIdx.x;
  const float invTC = 1.f / 0.07f;
  float a = (col ? SP[tid * 256 + i] : SP[i * 256 + tid]) * invTC;
  float b = (col ? SN[tid * 256 + i] : SN[i * 256 + tid]) * invTC;
  float mx = blockMax<4>(fmaxf(a, b));
  float se = blockSum<4>(__expf(a - mx) + __expf(b - mx));
  float lse = mx + __logf(se);
  if (tid == 0) {
    float diag = SP[i * 256 + i] * invTC;
    atomicAdd(out, -(diag - lse) * (1.f / 512.f));
  }
}

__global__ __launch_bounds__(256) void distcomb_k(
    const float* __restrict__ Pi, const float* __restrict__ Qj,
    const float* __restrict__ X, const float* __restrict__ V,
    float* __restrict__ val, float* __restrict__ out) {
  int i = blockIdx.x, j = threadIdx.x;
  float d = Pi[i] - 2.f * X[i * 256 + j] + Qj[j];
  float w = (i == j) ? 1.f : -V[i * 256 + j];
  float x = d * w;
  val[i * 256 + j] = x;
  __shared__ float diag_sh;
  if (j == i) diag_sh = x;
  float tot = blockSum<4>(x);
  if (j == 0) {
    float rs = diag_sh - (tot - diag_sh) * (1.f / 255.f);
    atomicAdd(out + 1, fmaxf(rs + 0.6f, 0.f) * (1.f / 512.f));
  }
}

__global__ __launch_bounds__(256) void loss4_k(const float* __restrict__ val,
                                               float* __restrict__ out) {
  int j = blockIdx.x, i = threadIdx.x;
  float x = val[i * 256 + j];
  __shared__ float diag_sh;
  if (i == j) diag_sh = x;
  float tot = blockSum<4>(x);
  if (i == 0) {
    float cs = diag_sh - (tot - diag_sh) * (1.f / 255.f);
    atomicAdd(out + 1, fmaxf(cs + 0.6f, 0.f) * (1.f / 512.f));
  }
}

// ---------------------------------------------------------------------------

extern "C" void kernel_launch(void* const* d_in, const int* in_sizes, int n_in,
                              void* d_out, int out_size, void* d_ws,
                              size_t ws_size, hipStream_t stream) {
  (void)in_sizes; (void)n_in; (void)out_size; (void)ws_size;
  const float* ev = (const float*)d_in[0];
  const float* ea = (const float*)d_in[1];
  const int* msk = (const int*)d_in[2];
  const float* Wf1 = (const float*)d_in[3];
  const float* Wf2 = (const float*)d_in[4];
  const float* Wc1 = (const float*)d_in[5];
  const float* Wc2 = (const float*)d_in[6];
  float* out = (float*)d_out;
  char* ws = (char*)d_ws;

  size_t off = 0;
  auto alloc = [&](size_t bytes) {
    void* p = ws + off;
    off = (off + bytes + 255) & ~(size_t)255;
    return p;
  };
  // Region 1: max(evb 6*RA*144 = 56.6 MB ; fv 50176*512*2 = 51.4 MB)
  unsigned short* evb = (unsigned short*)alloc((size_t)6 * RA * 144);
  unsigned short* fv = evb;  // reused after conv2
  // Region 2: max(x1b 8*RA*144 = 75.5 MB ; Sij 50176*256*4 = 51.4 MB)
  unsigned short* x1b = (unsigned short*)alloc((size_t)8 * RA * 144);
  float* Sij = (float*)x1b;  // reused after conv2
  unsigned short* wb1 = (unsigned short*)alloc((size_t)9 * 6 * 32768 * 2);
  unsigned short* wb2 = (unsigned short*)alloc((size_t)9 * 8 * 32768 * 2);
  unsigned short* eab = (unsigned short*)alloc((size_t)256 * 2048 * 2);
  unsigned short* wf1b = (unsigned short*)alloc((size_t)512 * 2048 * 2);
  unsigned short* wf2b = (unsigned short*)alloc((size_t)512 * 512 * 2);
  unsigned short* hb = (unsigned short*)alloc((size_t)256 * 512 * 2);
  float* fa = (float*)alloc((size_t)256 * 512 * 4);
  unsigned short* indnb = (unsigned short*)alloc((size_t)256 * 512 * 2);
  unsigned short* ivpb = (unsigned short*)alloc((size_t)256 * 512 * 2);
  unsigned short* fab = (unsigned short*)alloc((size_t)256 * 512 * 2);
  float* Pi = (float*)alloc(256 * 4);
  float* Qj = (float*)alloc(256 * 4);
  float* Xm = (float*)alloc((size_t)256 * 256 * 4);
  float* Vm = (float*)alloc((size_t)256 * 256 * 4);
  float* rn = (float*)alloc((size_t)50176 * 4);
  float* SP = (float*)alloc((size_t)256 * 256 * 4);
  float* SN = (float*)alloc((size_t)256 * 256 * 4);
  float* val = (float*)alloc((size_t)256 * 256 * 4);

  hipMemsetAsync(out, 0, 2 * sizeof(float), stream);

  prep_all_k<<<38656, 256, 0, stream>>>(ea, Wf1, Wf2, Wc1, Wc2, eab, wf1b,
                                        wf2b, wb1, wb2, (unsigned int*)x1b);
  evpad_k<<<dim3(256, 6), 256, 0, stream>>>(ev, evb);

  // conv1: relu, cell rows k-major (one image per block-x, N=512, K=9*384)
  convtap6_k<6, 0><<<dim3(256, 4), 256, 0, stream>>>(evb, wb1, x1b);
  // fc1 / fc2
  gemm1_k<2048, 512, 0><<<dim3(2, 4), 256, 0, stream>>>(eab, wf1b, hb, nullptr);
  gemm1_k<512, 512, 2><<<dim3(2, 4), 256, 0, stream>>>(hb, wf2b, fa, nullptr);
  // conv2: compact bf16 out (one image per block-x, N=512, K=9*512)
  convtap6_k<8, 1><<<dim3(256, 4), 256, 0, stream>>>(x1b, wb2, fv);

  pool_k<<<256, 512, 0, stream>>>(fv, msk, indnb, ivpb, Pi, rn);
  fanorm_k<<<256, 512, 0, stream>>>(fa, fab, Qj);

  // Sij[(i,p), j] = rn[i,p] * <fv[i,p,:], indn[j,:]>  (M=50176, N=256, K=512)
  gemm1_k<512, 256, 3><<<dim3(392, 2), 256, 0, stream>>>(fv, indnb, Sij, rn);
  gemm_xv_k<<<dim3(2, 2, 2), 256, 0, stream>>>(ivpb, fab, indnb, Xm, Vm);

  spsn_k<<<dim3(256, 4), 256, 0, stream>>>(Sij, SP, SN);
  loss12_k<<<512, 256, 0, stream>>>(SP, SN, out);
  distcomb_k<<<256, 256, 0, stream>>>(Pi, Qj, Xm, Vm, val, out);
  loss4_k<<<256, 256, 0, stream>>>(val, out);
}

// Round 3
// 833.008 us; speedup vs baseline: 1.0088x; 1.0088x over previous
//
#include <hip/hip_runtime.h>
#include <stdint.h>

// ---------------------------------------------------------------------------
// B=256, H=W=14, HW=196, TS=0.03, TC=0.07, TP_K=19, TN_K=98
// Conv inputs: padded 16x16 cell grid per image (1-cell zero halo):
// cell = b*256 + (h+1)*16 + (w+1). Conv 3x3 = 9 cell-row shifts d=dh*16+dw.
// convtap6_k: block = ONE image (M padded 196->224 rows) x 128 N. The A
// window per kc is EXACTLY the image's 256 cell rows (36.9 KB) — covers all
// 9 taps incl. halo with no clamping, no cross-image span. acc 7x4/wave.
// M-tiling: each 16x16 MFMA tile = a 2x8 PIXEL BLOCK of the padded grid
// (tq -> dh=tq>>3, dw=tq&7; mi -> h-pair 1+2*mi; wm -> w-half) so the A-read
// bank-start residue 4*((tq&7)+quad) is uniform per quarter-wave, all taps.
// B PATH (R2): weights in per-wave REGISTERS, DOUBLE-BUFFERED one step ahead
// (bwE/bwO, loop unrolled x2 for static indexing). Step s issues step s+1's
// 8 global_load_dwordx4 (L2-resident ~4.7MB weight set) BEFORE its MFMA
// cluster (~544 cy wall) -> L2 latency (~300 cy) fully hidden. R1 exposed
// this latency in-step and regressed; R0 hid it via LDS dbuf but paid
// per-step vmcnt(0)+barrier drains. R2 keeps R1's no-per-step-barrier
// structure (barriers ONLY at kc boundaries for the A restage).
// wb1/wb2 pre-packed in MFMA-fragment order: 1KB coalesced span per
// (n-group, K-half): off16 = (t*KC+kc)*4096 + g*128 + h*64 + lane.
// Grid 256x4 at 2 blocks/CU -> exactly 4 slots/CU, no tail quantization.
// NOTE: workspace regions are reused; size each by the MAX of its occupants.
// ---------------------------------------------------------------------------

typedef __attribute__((ext_vector_type(8))) short bf16x8;
typedef __attribute__((ext_vector_type(4))) float f32x4;

__device__ __forceinline__ unsigned short f2bf(float x) {
  unsigned u = __float_as_uint(x);
  unsigned r = u + 0x7FFFu + ((u >> 16) & 1u);  // RNE, no NaNs here
  return (unsigned short)(r >> 16);
}
__device__ __forceinline__ float bf2f(unsigned short h) {
  return __uint_as_float(((unsigned)h) << 16);
}

typedef const __attribute__((address_space(1))) void* gptr1_t;
typedef __attribute__((address_space(3))) void* lptr3_t;
__device__ __forceinline__ void gload_lds16(const void* g, void* l) {
  __builtin_amdgcn_global_load_lds((gptr1_t)g, (lptr3_t)l, 16, 0, 0);
}

__device__ __forceinline__ float waveSum(float v) {
#pragma unroll
  for (int m = 1; m < 64; m <<= 1) v += __shfl_xor(v, m, 64);
  return v;
}
__device__ __forceinline__ float waveMax(float v) {
#pragma unroll
  for (int m = 1; m < 64; m <<= 1) v = fmaxf(v, __shfl_xor(v, m, 64));
  return v;
}
template <int NW>
__device__ __forceinline__ float blockSum(float v) {
  __shared__ float sh[NW];
  v = waveSum(v);
  int wv = threadIdx.x >> 6, ln = threadIdx.x & 63;
  if (ln == 0) sh[wv] = v;
  __syncthreads();
  float r = 0.f;
#pragma unroll
  for (int w = 0; w < NW; ++w) r += sh[w];
  __syncthreads();
  return r;
}
template <int NW>
__device__ __forceinline__ float blockMax(float v) {
  __shared__ float sh[NW];
  v = waveMax(v);
  int wv = threadIdx.x >> 6, ln = threadIdx.x & 63;
  if (ln == 0) sh[wv] = v;
  __syncthreads();
  float r = -3.4e38f;
#pragma unroll
  for (int w = 0; w < NW; ++w) r = fmaxf(r, sh[w]);
  __syncthreads();
  return r;
}

#define RA 65536  // rows per k-slice of conv input buffers

// ---------------------------------------------------------------------------
// convtap6_k: one image per block-x. C[p,n] = sum_t sum_k A[cell(p)+d_t,k]B[t,n,k]
// 256 thr, 4 waves (wm in {0,1}: w-half, wn in {0,1}: 64 cols), acc 7x4 of
// 16x16x32 bf16 MFMA. A: [kc][RA][72] shorts (LDS window 256x72 = 36.9 KB).
// B: fragment-packed [t][kc][g(32)][h(2)][lane(64)][8] shorts, reg dbuf.
// EPI 0: relu -> x1b (cell rows, k-major slices). EPI 1: bf16 -> fv compact.
// ---------------------------------------------------------------------------
template <int KC, int EPI>
__global__ __launch_bounds__(256, 2) void convtap6_k(
    const unsigned short* __restrict__ A, const unsigned short* __restrict__ Bw,
    unsigned short* __restrict__ C) {
  __shared__ __align__(16) short Ah[256 * 72];
  const int tid = threadIdx.x;
  const int wave = tid >> 6, lane = tid & 63;
  const int wm = wave >> 1, wn = wave & 1;
  const int quad = lane >> 4, tq = lane & 15;
  const int img = blockIdx.x, n0 = blockIdx.y * 128;

  // A-row per MFMA tile: tile = 2x8 pixel block; lane tq -> (dh, dw).
  int pab[7];
  {
    const int dh = tq >> 3;
    int wq = wm * 8 + (tq & 7);          // w' in 0..15
    if (wq == 0) wq = 8;                 // dead col -> mirrored valid col,
    else if (wq == 15) wq = 7;           // same bank residue, taps in-bounds
#pragma unroll
    for (int mi = 0; mi < 7; ++mi) {
      int pr = (1 + 2 * mi + dh) * 16 + wq;  // h' in 1..14
      pab[mi] = pr * 72 + quad * 8;
    }
  }
  // B fragment base (16B units): (t*KC+kc)*4096 + g*128 + h*64 + lane
  const int gb = (n0 >> 4) + wn * 4;

  const char* Ab = (const char*)A;
  const int l16 = lane * 16;

  f32x4 acc[7][4];
#pragma unroll
  for (int mi = 0; mi < 7; ++mi)
#pragma unroll
    for (int ni = 0; ni < 4; ++ni) {
      f32x4 z = {0.f, 0.f, 0.f, 0.f};
      acc[mi][ni] = z;
    }

  auto stageA = [&](int kc) {
    size_t s0 = ((size_t)kc * RA + img * 256) * 144;
#pragma unroll
    for (int i = 0; i < 9; ++i) {
      int c = wave + i * 4;  // 36 chunks of 1024 B
      gload_lds16(Ab + s0 + (size_t)c * 1024 + l16, (char*)Ah + c * 1024);
    }
  };

  // load step-s B fragments (8x global_load_dwordx4, fully coalesced 1KB spans)
  auto loadB = [&](int s, bf16x8* bw) {
    int kc = s / 9, t = s - kc * 9;
    const int b16 = (t * KC + kc) * 4096 + gb * 128 + lane;
#pragma unroll
    for (int ni = 0; ni < 4; ++ni) {
      bw[ni] = *(const bf16x8*)&Bw[(size_t)(b16 + ni * 128) * 8];
      bw[4 + ni] = *(const bf16x8*)&Bw[(size_t)(b16 + ni * 128 + 64) * 8];
    }
  };

  // step-s MFMA cluster (uses bw prefetched one step earlier) + A restage
  auto compute = [&](int s, const bf16x8* bw) {
    int kc = s / 9, t = s - kc * 9;
    const int aoff = (((t / 3) - 1) * 16 + (t % 3) - 1) * 72;
    bf16x8 af0[7];
#pragma unroll
    for (int mi = 0; mi < 7; ++mi)
      af0[mi] = *(const bf16x8*)&Ah[pab[mi] + aoff];
#pragma unroll
    for (int mi = 0; mi < 7; ++mi)
#pragma unroll
      for (int ni = 0; ni < 4; ++ni)
        acc[mi][ni] = __builtin_amdgcn_mfma_f32_16x16x32_bf16(
            af0[mi], bw[ni], acc[mi][ni], 0, 0, 0);
    bf16x8 af1[7];
#pragma unroll
    for (int mi = 0; mi < 7; ++mi)
      af1[mi] = *(const bf16x8*)&Ah[pab[mi] + aoff + 32];
#pragma unroll
    for (int mi = 0; mi < 7; ++mi)
#pragma unroll
      for (int ni = 0; ni < 4; ++ni)
        acc[mi][ni] = __builtin_amdgcn_mfma_f32_16x16x32_bf16(
            af1[mi], bw[4 + ni], acc[mi][ni], 0, 0, 0);
    if (t == 8 && kc + 1 < KC) {  // A window restage at kc boundary
      __syncthreads();
      stageA(kc + 1);
      __syncthreads();
    }
  };

  stageA(0);
  bf16x8 bwE[8], bwO[8];
  loadB(0, bwE);  // overlaps the A staging + barrier
  __syncthreads();

  const int NS = KC * 9;  // even (54 or 72)
#pragma unroll 1
  for (int s = 0; s < NS; s += 2) {
    loadB(s + 1, bwO);              // prefetch next step (hidden under MFMAs)
    compute(s, bwE);
    if (s + 2 < NS) loadB(s + 2, bwE);
    compute(s + 1, bwO);
  }

#pragma unroll
  for (int mi = 0; mi < 7; ++mi) {
#pragma unroll
    for (int r = 0; r < 4; ++r) {
      int idx = quad * 4 + r;            // M-row within tile, 0..15
      int wv = wm * 8 + (idx & 7);       // w' in 0..15
      if (wv == 0 || wv == 15) continue;  // dead column (halo)
      int hh = 1 + 2 * mi + (idx >> 3);  // h' in 1..14
      if (EPI == 0) {
        int cell = img * 256 + hh * 16 + wv;
        int slice = (n0 >> 6) + wn;
        size_t ob = ((size_t)slice * RA + cell) * 72 + tq;
#pragma unroll
        for (int ni = 0; ni < 4; ++ni)
          C[ob + ni * 16] = f2bf(fmaxf(acc[mi][ni][r], 0.f));
      } else {
        int p = (hh - 1) * 14 + (wv - 1);
        size_t ob = (size_t)(img * 196 + p) * 512 + n0 + wn * 64 + tq;
#pragma unroll
        for (int ni = 0; ni < 4; ++ni)
          C[ob + ni * 16] = f2bf(acc[mi][ni][r]);
      }
    }
  }
}

// ---------------------------------------------------------------------------
// gemm1_k: C[m,n] = sum_k A[m,k]*B[n,k]; 128x128 tile, 4 waves, BK=64,
// XOR-swizzled LDS. EPI: 0 relu->bf16, 2 f32, 3 f32 * rs[m] (row scale).
// ---------------------------------------------------------------------------
template <int K, int NLD, int EPI>
__global__ __launch_bounds__(256, 2) void gemm1_k(
    const unsigned short* __restrict__ A, const unsigned short* __restrict__ Bw,
    void* __restrict__ C, const float* __restrict__ rs) {
  __shared__ short As[128 * 64];
  __shared__ short Bs[128 * 64];
  const int tid = threadIdx.x;
  const int wave = tid >> 6, lane = tid & 63;
  const int m0 = blockIdx.x * 128, n0 = blockIdx.y * 128;
  const int rr8 = lane >> 3, seg = lane & 7, gseg = seg ^ rr8;
  const int wm = wave >> 1, wn = wave & 1;
  const int quad = lane >> 4, tq = lane & 15;

  size_t asrc[4], bsrc[4];
#pragma unroll
  for (int i8 = 0; i8 < 4; ++i8) {
    int rloc = wave * 32 + i8 * 8 + rr8;
    asrc[i8] = (size_t)(m0 + rloc) * K + gseg * 8;
    bsrc[i8] = (size_t)(n0 + rloc) * K + gseg * 8;
  }

  f32x4 acc[4][4];
#pragma unroll
  for (int mi = 0; mi < 4; ++mi)
#pragma unroll
    for (int ni = 0; ni < 4; ++ni) {
      f32x4 z = {0.f, 0.f, 0.f, 0.f};
      acc[mi][ni] = z;
    }

#pragma unroll 1
  for (int kc2 = 0; kc2 < K / 64; ++kc2) {
    int kb = kc2 * 64;
    __syncthreads();
#pragma unroll
    for (int i8 = 0; i8 < 4; ++i8) {
      gload_lds16(A + asrc[i8] + kb, &As[(wave * 32 + i8 * 8) * 64]);
      gload_lds16(Bw + bsrc[i8] + kb, &Bs[(wave * 32 + i8 * 8) * 64]);
    }
    __syncthreads();
#pragma unroll
    for (int h = 0; h < 2; ++h) {
      bf16x8 af[4], bfr[4];
#pragma unroll
      for (int mi = 0; mi < 4; ++mi) {
        int row = wm * 64 + mi * 16 + tq;
        af[mi] = *(const bf16x8*)&As[row * 64 +
                                     ((((h << 2) | quad) ^ (row & 7)) << 3)];
      }
#pragma unroll
      for (int ni = 0; ni < 4; ++ni) {
        int row = wn * 64 + ni * 16 + tq;
        bfr[ni] = *(const bf16x8*)&Bs[row * 64 +
                                      ((((h << 2) | quad) ^ (row & 7)) << 3)];
      }
#pragma unroll
      for (int mi = 0; mi < 4; ++mi)
#pragma unroll
        for (int ni = 0; ni < 4; ++ni)
          acc[mi][ni] = __builtin_amdgcn_mfma_f32_16x16x32_bf16(
              af[mi], bfr[ni], acc[mi][ni], 0, 0, 0);
    }
  }

#pragma unroll
  for (int mi = 0; mi < 4; ++mi) {
#pragma unroll
    for (int r = 0; r < 4; ++r) {
      int m = m0 + wm * 64 + mi * 16 + quad * 4 + r;
      float sc = (EPI == 3) ? rs[m] : 1.f;
      size_t obase = (size_t)m * NLD + n0 + wn * 64 + tq;
#pragma unroll
      for (int ni = 0; ni < 4; ++ni) {
        float v = acc[mi][ni][r];
        size_t idx = obase + ni * 16;
        if (EPI == 0)
          ((unsigned short*)C)[idx] = f2bf(fmaxf(v, 0.f));
        else if (EPI == 2)
          ((float*)C)[idx] = v;
        else
          ((float*)C)[idx] = v * sc;
      }
    }
  }
}

// Xm = (iv+eps).fa^T and Vm = indn.indn^T in one dispatch (blockIdx.z picks)
__global__ __launch_bounds__(256, 2) void gemm_xv_k(
    const unsigned short* __restrict__ ivpb, const unsigned short* __restrict__ fab,
    const unsigned short* __restrict__ indnb, float* __restrict__ Xm,
    float* __restrict__ Vm) {
  const unsigned short* A = blockIdx.z ? indnb : ivpb;
  const unsigned short* Bw = blockIdx.z ? indnb : fab;
  float* C = blockIdx.z ? Vm : Xm;
  __shared__ short As[128 * 64];
  __shared__ short Bs[128 * 64];
  const int tid = threadIdx.x;
  const int wave = tid >> 6, lane = tid & 63;
  const int m0 = blockIdx.x * 128, n0 = blockIdx.y * 128;
  const int rr8 = lane >> 3, seg = lane & 7, gseg = seg ^ rr8;
  const int wm = wave >> 1, wn = wave & 1;
  const int quad = lane >> 4, tq = lane & 15;
  size_t asrc[4], bsrc[4];
#pragma unroll
  for (int i8 = 0; i8 < 4; ++i8) {
    int rloc = wave * 32 + i8 * 8 + rr8;
    asrc[i8] = (size_t)(m0 + rloc) * 512 + gseg * 8;
    bsrc[i8] = (size_t)(n0 + rloc) * 512 + gseg * 8;
  }
  f32x4 acc[4][4];
#pragma unroll
  for (int mi = 0; mi < 4; ++mi)
#pragma unroll
    for (int ni = 0; ni < 4; ++ni) {
      f32x4 z = {0.f, 0.f, 0.f, 0.f};
      acc[mi][ni] = z;
    }
#pragma unroll 1
  for (int kc2 = 0; kc2 < 8; ++kc2) {
    int kb = kc2 * 64;
    __syncthreads();
#pragma unroll
    for (int i8 = 0; i8 < 4; ++i8) {
      gload_lds16(A + asrc[i8] + kb, &As[(wave * 32 + i8 * 8) * 64]);
      gload_lds16(Bw + bsrc[i8] + kb, &Bs[(wave * 32 + i8 * 8) * 64]);
    }
    __syncthreads();
#pragma unroll
    for (int h = 0; h < 2; ++h) {
      bf16x8 af[4], bfr[4];
#pragma unroll
      for (int mi = 0; mi < 4; ++mi) {
        int row = wm * 64 + mi * 16 + tq;
        af[mi] = *(const bf16x8*)&As[row * 64 +
                                     ((((h << 2) | quad) ^ (row & 7)) << 3)];
      }
#pragma unroll
      for (int ni = 0; ni < 4; ++ni) {
        int row = wn * 64 + ni * 16 + tq;
        bfr[ni] = *(const bf16x8*)&Bs[row * 64 +
                                      ((((h << 2) | quad) ^ (row & 7)) << 3)];
      }
#pragma unroll
      for (int mi = 0; mi < 4; ++mi)
#pragma unroll
        for (int ni = 0; ni < 4; ++ni)
          acc[mi][ni] = __builtin_amdgcn_mfma_f32_16x16x32_bf16(
              af[mi], bfr[ni], acc[mi][ni], 0, 0, 0);
    }
  }
#pragma unroll
  for (int mi = 0; mi < 4; ++mi)
#pragma unroll
    for (int r = 0; r < 4; ++r) {
      int m = m0 + wm * 64 + mi * 16 + quad * 4 + r;
      size_t obase = (size_t)m * 256 + n0 + wn * 64 + tq;
#pragma unroll
      for (int ni = 0; ni < 4; ++ni) C[obase + ni * 16] = acc[mi][ni][r];
    }
}

// --------------------------- prep (fused) ----------------------------------
// ranges: ea/Wf1/Wf2 casts | wb1 build | wb2 build | x1b halo zeroing
// wb layout (fragment-packed): flat index j =
//   (((t*KC+kc)*32 + g)*2 + h)*512 + quad*128 + tq*8 + jj
// value = Wc[n = g*16+tq][cin = kc*64 + h*32 + quad*8 + jj][tap t]
// -> writes are perfectly linear; the conv kernel reads 1KB coalesced spans.
__global__ void prep_all_k(const float* __restrict__ ea,
                           const float* __restrict__ Wf1,
                           const float* __restrict__ Wf2,
                           const float* __restrict__ Wc1,
                           const float* __restrict__ Wc2,
                           unsigned short* __restrict__ eab,
                           unsigned short* __restrict__ wf1b,
                           unsigned short* __restrict__ wf2b,
                           unsigned short* __restrict__ wb1,
                           unsigned short* __restrict__ wb2,
                           unsigned int* __restrict__ x1u) {
  int i = blockIdx.x * 256 + threadIdx.x;
  if (i < 524288) {
    eab[i] = f2bf(ea[i]);
  } else if (i < 1572864) {
    int j = i - 524288;
    wf1b[j] = f2bf(Wf1[j]);
  } else if (i < 1835008) {
    int j = i - 1572864;
    wf2b[j] = f2bf(Wf2[j]);
  } else if (i < 3604480) {
    int j = i - 1835008;  // wb1: 9*6*32768 fragment-packed <- Wc1[n][384][3][3]
    int t = j / (6 * 32768), r = j - t * (6 * 32768);
    int kc = r / 32768, r2 = r - kc * 32768;
    int g = r2 >> 10, h = (r2 >> 9) & 1, quad = (r2 >> 7) & 3;
    int tq = (r2 >> 3) & 15, jj = r2 & 7;
    int n = g * 16 + tq, cin = kc * 64 + h * 32 + quad * 8 + jj;
    wb1[j] = f2bf(Wc1[(n * 384 + cin) * 9 + t]);
  } else if (i < 5963776) {
    int j = i - 3604480;  // wb2: 9*8*32768 fragment-packed <- Wc2[n][512][3][3]
    int t = j / (8 * 32768), r = j - t * (8 * 32768);
    int kc = r / 32768, r2 = r - kc * 32768;
    int g = r2 >> 10, h = (r2 >> 9) & 1, quad = (r2 >> 7) & 3;
    int tq = (r2 >> 3) & 15, jj = r2 & 7;
    int n = g * 16 + tq, cin = kc * 64 + h * 32 + quad * 8 + jj;
    wb2[j] = f2bf(Wc2[(n * 512 + cin) * 9 + t]);
  } else {
    int j = i - 5963776;  // 15360 halo rows x 8 slices x 32 uints
    int hr = j >> 8, u = j & 255;
    int slice = u >> 5, uu = u & 31;
    int b = hr / 60, c = hr - b * 60;
    int cell;
    if (c < 16) cell = c;
    else if (c < 32) cell = 240 + (c - 16);
    else if (c < 46) cell = (c - 31) * 16;
    else cell = (c - 45) * 16 + 15;
    x1u[((size_t)slice * RA + b * 256 + cell) * 36 + uu] = 0u;
  }
}

// ev (256,384,14,14) fp32 -> evb [kc6][RA][72] bf16 (halo cells zero)
__global__ __launch_bounds__(256) void evpad_k(const float* __restrict__ ev,
                                               unsigned short* __restrict__ out) {
  int b = blockIdx.x, ct = blockIdx.y;  // channel tile: c0 = ct*64
  __shared__ float tile[64][197];
  int tid = threadIdx.x;
  const float* src = ev + ((size_t)b * 384 + ct * 64) * 196;
#pragma unroll 1
  for (int it = 0; it < 49; ++it) {
    int idx = it * 256 + tid;
    int c = idx / 196, p = idx - c * 196;
    tile[c][p] = src[idx];
  }
  __syncthreads();
  unsigned short* dst = out + ((size_t)ct * RA + b * 256) * 72;
#pragma unroll 1
  for (int it = 0; it < 64; ++it) {
    int idx = it * 256 + tid;
    int cell = idx >> 6, c = idx & 63;
    int h = (cell >> 4) - 1, w = (cell & 15) - 1;
    float v = ((unsigned)h < 14u && (unsigned)w < 14u) ? tile[c][h * 14 + w]
                                                       : 0.f;
    dst[(size_t)cell * 72 + c] = f2bf(v);
  }
}

// --------------------------- pooling / norms -------------------------------

// fused: masked mean pool + per-pixel inverse norm (rn) + ind normalization
__global__ __launch_bounds__(512) void pool_k(
    const unsigned short* __restrict__ fv, const int* __restrict__ masks,
    unsigned short* __restrict__ indnb, unsigned short* __restrict__ ivpb,
    float* __restrict__ Pi, float* __restrict__ rn) {
  int b = blockIdx.x;
  int w = threadIdx.x >> 6, lane = threadIdx.x & 63;
  __shared__ float red[8][512];
  __shared__ float msh[8];
  float acc[8] = {0.f, 0.f, 0.f, 0.f, 0.f, 0.f, 0.f, 0.f};
  float msum = 0.f;
  for (int p = w; p < 196; p += 8) {
    float m = (float)masks[b * 196 + p];
    msum += m;
    uint4 d = *(const uint4*)(fv + (size_t)(b * 196 + p) * 512 + lane * 8);
    const unsigned short* hp = (const unsigned short*)&d;
    float ss = 0.f;
#pragma unroll
    for (int k = 0; k < 8; ++k) {
      float x = bf2f(hp[k]);
      ss += x * x;
      acc[k] += m * x;
    }
    ss = waveSum(ss);
    if (lane == 0) rn[b * 196 + p] = 1.f / fmaxf(sqrtf(ss), 1e-12f);
  }
#pragma unroll
  for (int k = 0; k < 8; ++k) red[w][lane * 8 + k] = acc[k];
  if (lane == 0) msh[w] = msum;
  __syncthreads();
  int tid = threadIdx.x;
  float s = 0.f, mtot = 0.f;
#pragma unroll
  for (int ww = 0; ww < 8; ++ww) {
    s += red[ww][tid];
    mtot += msh[ww];
  }
  float v = s / mtot;  // indv[b, tid]
  float ss2 = blockSum<8>(v * v);
  float sc = 1.f / fmaxf(sqrtf(ss2), 1e-12f);
  indnb[b * 512 + tid] = f2bf(v * sc);
  float ve = v + 1e-6f;
  ivpb[b * 512 + tid] = f2bf(ve);
  float p2 = blockSum<8>(ve * ve);
  if (tid == 0) Pi[b] = p2;
}

// fa fp32 -> bf16 + Qj = ||fa_j||^2
__global__ __launch_bounds__(512) void fanorm_k(const float* __restrict__ fa,
                                                unsigned short* __restrict__ fab,
                                                float* __restrict__ Qj) {
  int b = blockIdx.x, tid = threadIdx.x;
  float v = fa[b * 512 + tid];
  fab[b * 512 + tid] = f2bf(v);
  float q = blockSum<8>(v * v);
  if (tid == 0) Qj[b] = q;
}

// ------------------------------ SP / SN ------------------------------------

__device__ __forceinline__ float radix_kth(unsigned k0, unsigned k1, unsigned k2,
                                           unsigned k3, int k) {
  unsigned prefix = 0;
  int kk = k;
#pragma unroll 1
  for (int bit = 31; bit >= 14; --bit) {  // 18 steps; thr err ~2^-9 rel, ok
    unsigned thi = (prefix >> bit) | 1u;
    int c = __popcll(__ballot((k0 >> bit) == thi)) +
            __popcll(__ballot((k1 >> bit) == thi)) +
            __popcll(__ballot((k2 >> bit) == thi)) +
            __popcll(__ballot((k3 >> bit) == thi));
    if (kk <= c)
      prefix |= (1u << bit);
    else
      kk -= c;
  }
  unsigned u = (prefix & 0x80000000u) ? (prefix ^ 0x80000000u) : ~prefix;
  return __uint_as_float(u);
}
__device__ __forceinline__ unsigned sortkey(float x) {
  unsigned u = __float_as_uint(x);
  return u ^ (((int)u >> 31) | 0x80000000u);
}

__global__ __launch_bounds__(256) void spsn_k(const float* __restrict__ Sij,
                                              float* __restrict__ SP,
                                              float* __restrict__ SN) {
  int i = blockIdx.x, jg = blockIdx.y;
  int tid = threadIdx.x, wave = tid >> 6, lane = tid & 63;
  __shared__ float tile[196 * 65];
#pragma unroll 1
  for (int it = 0; it < 49; ++it) {
    int lin = it * 256 + tid;
    int p = lin >> 6, j = lin & 63;
    tile[p * 65 + j] = Sij[(size_t)(i * 196 + p) * 256 + jg * 64 + j];
  }
  __syncthreads();
#pragma unroll 1
  for (int jj = 0; jj < 16; ++jj) {
    int j = jj * 4 + wave;
    float v0 = tile[lane * 65 + j];
    float v1 = tile[(lane + 64) * 65 + j];
    float v2 = tile[(lane + 128) * 65 + j];
    bool val3 = lane < 4;
    float v3 = val3 ? tile[(lane + 192) * 65 + j] : 0.f;
    unsigned k0 = sortkey(v0), k1 = sortkey(v1), k2 = sortkey(v2);
    unsigned k3 = val3 ? sortkey(v3) : 0u;
    float thrP = radix_kth(k0, k1, k2, k3, 19);
    float thrN = radix_kth(k0, k1, k2, k3, 99);
    float spn = 0.f, spd = 0.f, snn = 0.f, snd = 0.f;
    const float invTS = 1.f / 0.03f;
#pragma unroll
    for (int q = 0; q < 4; ++q) {
      float v = (q == 0) ? v0 : (q == 1) ? v1 : (q == 2) ? v2 : v3;
      bool ok = (q < 3) || val3;
      if (ok) {
        float mp = 1.f / (1.f + __expf((thrP - v) * invTS));
        float mn = 1.f / (1.f + __expf((v - thrN) * invTS));
        spn += v * mp;
        spd += mp;
        snn += v * mn;
        snd += mn;
      }
    }
    spn = waveSum(spn); spd = waveSum(spd);
    snn = waveSum(snn); snd = waveSum(snd);
    if (lane == 0) {
      SP[i * 256 + jg * 64 + j] = spn / spd;
      SN[i * 256 + jg * 64 + j] = snn / snd;
    }
  }
}

__global__ __launch_bounds__(256) void loss12_k(const float* __restrict__ SP,
                                                const float* __restrict__ SN,
                                                float* __restrict__ out) {
  int r = blockIdx.x;
  int i = r & 255;
  bool col = r >= 256;
  int tid = threadIdx.x;
  const float invTC = 1.f / 0.07f;
  float a = (col ? SP[tid * 256 + i] : SP[i * 256 + tid]) * invTC;
  float b = (col ? SN[tid * 256 + i] : SN[i * 256 + tid]) * invTC;
  float mx = blockMax<4>(fmaxf(a, b));
  float se = blockSum<4>(__expf(a - mx) + __expf(b - mx));
  float lse = mx + __logf(se);
  if (tid == 0) {
    float diag = SP[i * 256 + i] * invTC;
    atomicAdd(out, -(diag - lse) * (1.f / 512.f));
  }
}

__global__ __launch_bounds__(256) void distcomb_k(
    const float* __restrict__ Pi, const float* __restrict__ Qj,
    const float* __restrict__ X, const float* __restrict__ V,
    float* __restrict__ val, float* __restrict__ out) {
  int i = blockIdx.x, j = threadIdx.x;
  float d = Pi[i] - 2.f * X[i * 256 + j] + Qj[j];
  float w = (i == j) ? 1.f : -V[i * 256 + j];
  float x = d * w;
  val[i * 256 + j] = x;
  __shared__ float diag_sh;
  if (j == i) diag_sh = x;
  float tot = blockSum<4>(x);
  if (j == 0) {
    float rs = diag_sh - (tot - diag_sh) * (1.f / 255.f);
    atomicAdd(out + 1, fmaxf(rs + 0.6f, 0.f) * (1.f / 512.f));
  }
}

__global__ __launch_bounds__(256) void loss4_k(const float* __restrict__ val,
                                               float* __restrict__ out) {
  int j = blockIdx.x, i = threadIdx.x;
  float x = val[i * 256 + j];
  __shared__ float diag_sh;
  if (i == j) diag_sh = x;
  float tot = blockSum<4>(x);
  if (i == 0) {
    float cs = diag_sh - (tot - diag_sh) * (1.f / 255.f);
    atomicAdd(out + 1, fmaxf(cs + 0.6f, 0.f) * (1.f / 512.f));
  }
}

// ---------------------------------------------------------------------------

extern "C" void kernel_launch(void* const* d_in, const int* in_sizes, int n_in,
                              void* d_out, int out_size, void* d_ws,
                              size_t ws_size, hipStream_t stream) {
  (void)in_sizes; (void)n_in; (void)out_size; (void)ws_size;
  const float* ev = (const float*)d_in[0];
  const float* ea = (const float*)d_in[1];
  const int* msk = (const int*)d_in[2];
  const float* Wf1 = (const float*)d_in[3];
  const float* Wf2 = (const float*)d_in[4];
  const float* Wc1 = (const float*)d_in[5];
  const float* Wc2 = (const float*)d_in[6];
  float* out = (float*)d_out;
  char* ws = (char*)d_ws;

  size_t off = 0;
  auto alloc = [&](size_t bytes) {
    void* p = ws + off;
    off = (off + bytes + 255) & ~(size_t)255;
    return p;
  };
  // Region 1: max(evb 6*RA*144 = 56.6 MB ; fv 50176*512*2 = 51.4 MB)
  unsigned short* evb = (unsigned short*)alloc((size_t)6 * RA * 144);
  unsigned short* fv = evb;  // reused after conv2
  // Region 2: max(x1b 8*RA*144 = 75.5 MB ; Sij 50176*256*4 = 51.4 MB)
  unsigned short* x1b = (unsigned short*)alloc((size_t)8 * RA * 144);
  float* Sij = (float*)x1b;  // reused after conv2
  unsigned short* wb1 = (unsigned short*)alloc((size_t)9 * 6 * 32768 * 2);
  unsigned short* wb2 = (unsigned short*)alloc((size_t)9 * 8 * 32768 * 2);
  unsigned short* eab = (unsigned short*)alloc((size_t)256 * 2048 * 2);
  unsigned short* wf1b = (unsigned short*)alloc((size_t)512 * 2048 * 2);
  unsigned short* wf2b = (unsigned short*)alloc((size_t)512 * 512 * 2);
  unsigned short* hb = (unsigned short*)alloc((size_t)256 * 512 * 2);
  float* fa = (float*)alloc((size_t)256 * 512 * 4);
  unsigned short* indnb = (unsigned short*)alloc((size_t)256 * 512 * 2);
  unsigned short* ivpb = (unsigned short*)alloc((size_t)256 * 512 * 2);
  unsigned short* fab = (unsigned short*)alloc((size_t)256 * 512 * 2);
  float* Pi = (float*)alloc(256 * 4);
  float* Qj = (float*)alloc(256 * 4);
  float* Xm = (float*)alloc((size_t)256 * 256 * 4);
  float* Vm = (float*)alloc((size_t)256 * 256 * 4);
  float* rn = (float*)alloc((size_t)50176 * 4);
  float* SP = (float*)alloc((size_t)256 * 256 * 4);
  float* SN = (float*)alloc((size_t)256 * 256 * 4);
  float* val = (float*)alloc((size_t)256 * 256 * 4);

  hipMemsetAsync(out, 0, 2 * sizeof(float), stream);

  prep_all_k<<<38656, 256, 0, stream>>>(ea, Wf1, Wf2, Wc1, Wc2, eab, wf1b,
                                        wf2b, wb1, wb2, (unsigned int*)x1b);
  evpad_k<<<dim3(256, 6), 256, 0, stream>>>(ev, evb);

  // conv1: relu, cell rows k-major (one image per block-x, N=512, K=9*384)
  convtap6_k<6, 0><<<dim3(256, 4), 256, 0, stream>>>(evb, wb1, x1b);
  // fc1 / fc2
  gemm1_k<2048, 512, 0><<<dim3(2, 4), 256, 0, stream>>>(eab, wf1b, hb, nullptr);
  gemm1_k<512, 512, 2><<<dim3(2, 4), 256, 0, stream>>>(hb, wf2b, fa, nullptr);
  // conv2: compact bf16 out (one image per block-x, N=512, K=9*512)
  convtap6_k<8, 1><<<dim3(256, 4), 256, 0, stream>>>(x1b, wb2, fv);

  pool_k<<<256, 512, 0, stream>>>(fv, msk, indnb, ivpb, Pi, rn);
  fanorm_k<<<256, 512, 0, stream>>>(fa, fab, Qj);

  // Sij[(i,p), j] = rn[i,p] * <fv[i,p,:], indn[j,:]>  (M=50176, N=256, K=512)
  gemm1_k<512, 256, 3><<<dim3(392, 2), 256, 0, stream>>>(fv, indnb, Sij, rn);
  gemm_xv_k<<<dim3(2, 2, 2), 256, 0, stream>>>(ivpb, fab, indnb, Xm, Vm);

  spsn_k<<<dim3(256, 4), 256, 0, stream>>>(Sij, SP, SN);
  loss12_k<<<512, 256, 0, stream>>>(SP, SN, out);
  distcomb_k<<<256, 256, 0, stream>>>(Pi, Qj, Xm, Vm, val, out);
  loss4_k<<<256, 256, 0, stream>>>(val, out);
}

// Round 4
// 807.811 us; speedup vs baseline: 1.0403x; 1.0312x over previous
//
#include <hip/hip_runtime.h>
#include <stdint.h>

// ---------------------------------------------------------------------------
// B=256, H=W=14, HW=196, TS=0.03, TC=0.07, TP_K=19, TN_K=98
// Conv inputs: padded 16x16 cell grid per image (1-cell zero halo):
// cell = b*256 + (h+1)*16 + (w+1). Conv 3x3 = 9 cell-row shifts d=dh*16+dw.
// convtap6_k: block = ONE image (M padded 196->224 rows) x 128 N. The A
// window per kc is EXACTLY the image's 256 cell rows (36.9 KB) — covers all
// 9 taps incl. halo with no clamping, no cross-image span. acc 7x4/wave.
// M-tiling: each 16x16 MFMA tile = a 2x8 PIXEL BLOCK of the padded grid
// (tq -> dh=tq>>3, dw=tq&7; mi -> h-pair 1+2*mi; wm -> w-half) so the A-read
// bank-start residue 4*((tq&7)+quad) is uniform per quarter-wave, all taps.
// B PATH (R2): weights in per-wave REGISTERS, DOUBLE-BUFFERED one step ahead
// (bwE/bwO, loop unrolled x2 for static indexing). Step s issues step s+1's
// 8 global_load_dwordx4 BEFORE its MFMA cluster -> load latency hidden.
// XCD REMAP (R4): flat block id -> xcd = flat&7 (round-robin dispatch);
// n0 quarter = xcd&3, img = (xcd>>2)*128 + flat>>3 (bijective). Each XCD
// then touches ONE weight quarter (1.18 MB conv2 / 0.88 MB conv1) + ~64
// concurrent 36.9 KB A slices ~= 3.5 MB -> fits 4 MB per-XCD L2. R3's
// default mapping put ALL 4 quarters (4.7 MB) on every XCD -> L2 thrash
// (FETCH 170 MB/dispatch, weights + A refetched from HBM/L3).
// wb1/wb2 pre-packed in MFMA-fragment order: 1KB coalesced span per
// (n-group, K-half): off16 = (t*KC+kc)*4096 + g*128 + h*64 + lane.
// Grid 256x4 at 2 blocks/CU -> exactly 4 slots/CU, no tail quantization.
// NOTE: workspace regions are reused; size each by the MAX of its occupants.
// ---------------------------------------------------------------------------

typedef __attribute__((ext_vector_type(8))) short bf16x8;
typedef __attribute__((ext_vector_type(4))) float f32x4;

__device__ __forceinline__ unsigned short f2bf(float x) {
  unsigned u = __float_as_uint(x);
  unsigned r = u + 0x7FFFu + ((u >> 16) & 1u);  // RNE, no NaNs here
  return (unsigned short)(r >> 16);
}
__device__ __forceinline__ float bf2f(unsigned short h) {
  return __uint_as_float(((unsigned)h) << 16);
}

typedef const __attribute__((address_space(1))) void* gptr1_t;
typedef __attribute__((address_space(3))) void* lptr3_t;
__device__ __forceinline__ void gload_lds16(const void* g, void* l) {
  __builtin_amdgcn_global_load_lds((gptr1_t)g, (lptr3_t)l, 16, 0, 0);
}

__device__ __forceinline__ float waveSum(float v) {
#pragma unroll
  for (int m = 1; m < 64; m <<= 1) v += __shfl_xor(v, m, 64);
  return v;
}
__device__ __forceinline__ float waveMax(float v) {
#pragma unroll
  for (int m = 1; m < 64; m <<= 1) v = fmaxf(v, __shfl_xor(v, m, 64));
  return v;
}
template <int NW>
__device__ __forceinline__ float blockSum(float v) {
  __shared__ float sh[NW];
  v = waveSum(v);
  int wv = threadIdx.x >> 6, ln = threadIdx.x & 63;
  if (ln == 0) sh[wv] = v;
  __syncthreads();
  float r = 0.f;
#pragma unroll
  for (int w = 0; w < NW; ++w) r += sh[w];
  __syncthreads();
  return r;
}
template <int NW>
__device__ __forceinline__ float blockMax(float v) {
  __shared__ float sh[NW];
  v = waveMax(v);
  int wv = threadIdx.x >> 6, ln = threadIdx.x & 63;
  if (ln == 0) sh[wv] = v;
  __syncthreads();
  float r = -3.4e38f;
#pragma unroll
  for (int w = 0; w < NW; ++w) r = fmaxf(r, sh[w]);
  __syncthreads();
  return r;
}

#define RA 65536  // rows per k-slice of conv input buffers

// ---------------------------------------------------------------------------
// convtap6_k: one image per (remapped) block. C[p,n] = sum_t sum_k
// A[cell(p)+d_t,k]*B[t,n,k]. 256 thr, 4 waves (wm: w-half, wn: 64-col half),
// acc 7x4 of 16x16x32 bf16 MFMA. A: [kc][RA][72] shorts (LDS 256x72=36.9KB).
// B: fragment-packed [t][kc][g(32)][h(2)][lane(64)][8] shorts, reg dbuf.
// EPI 0: relu -> x1b (cell rows, k-major slices). EPI 1: bf16 -> fv compact.
// ---------------------------------------------------------------------------
template <int KC, int EPI>
__global__ __launch_bounds__(256, 2) void convtap6_k(
    const unsigned short* __restrict__ A, const unsigned short* __restrict__ Bw,
    unsigned short* __restrict__ C) {
  __shared__ __align__(16) short Ah[256 * 72];
  const int tid = threadIdx.x;
  const int wave = tid >> 6, lane = tid & 63;
  const int wm = wave >> 1, wn = wave & 1;
  const int quad = lane >> 4, tq = lane & 15;
  // XCD-aware bijective remap: one n0 quarter per XCD (see header comment)
  const int flat = blockIdx.x + (blockIdx.y << 8);
  const int xcd = flat & 7;
  const int img = ((xcd >> 2) << 7) + (flat >> 3);
  const int n0 = (xcd & 3) * 128;

  // A-row per MFMA tile: tile = 2x8 pixel block; lane tq -> (dh, dw).
  int pab[7];
  {
    const int dh = tq >> 3;
    int wq = wm * 8 + (tq & 7);          // w' in 0..15
    if (wq == 0) wq = 8;                 // dead col -> mirrored valid col,
    else if (wq == 15) wq = 7;           // same bank residue, taps in-bounds
#pragma unroll
    for (int mi = 0; mi < 7; ++mi) {
      int pr = (1 + 2 * mi + dh) * 16 + wq;  // h' in 1..14
      pab[mi] = pr * 72 + quad * 8;
    }
  }
  // B fragment base (16B units): (t*KC+kc)*4096 + g*128 + h*64 + lane
  const int gb = (n0 >> 4) + wn * 4;

  const char* Ab = (const char*)A;
  const int l16 = lane * 16;

  f32x4 acc[7][4];
#pragma unroll
  for (int mi = 0; mi < 7; ++mi)
#pragma unroll
    for (int ni = 0; ni < 4; ++ni) {
      f32x4 z = {0.f, 0.f, 0.f, 0.f};
      acc[mi][ni] = z;
    }

  auto stageA = [&](int kc) {
    size_t s0 = ((size_t)kc * RA + img * 256) * 144;
#pragma unroll
    for (int i = 0; i < 9; ++i) {
      int c = wave + i * 4;  // 36 chunks of 1024 B
      gload_lds16(Ab + s0 + (size_t)c * 1024 + l16, (char*)Ah + c * 1024);
    }
  };

  // load step-s B fragments (8x global_load_dwordx4, fully coalesced 1KB spans)
  auto loadB = [&](int s, bf16x8* bw) {
    int kc = s / 9, t = s - kc * 9;
    const int b16 = (t * KC + kc) * 4096 + gb * 128 + lane;
#pragma unroll
    for (int ni = 0; ni < 4; ++ni) {
      bw[ni] = *(const bf16x8*)&Bw[(size_t)(b16 + ni * 128) * 8];
      bw[4 + ni] = *(const bf16x8*)&Bw[(size_t)(b16 + ni * 128 + 64) * 8];
    }
  };

  // step-s MFMA cluster (uses bw prefetched one step earlier) + A restage
  auto compute = [&](int s, const bf16x8* bw) {
    int kc = s / 9, t = s - kc * 9;
    const int aoff = (((t / 3) - 1) * 16 + (t % 3) - 1) * 72;
    bf16x8 af0[7];
#pragma unroll
    for (int mi = 0; mi < 7; ++mi)
      af0[mi] = *(const bf16x8*)&Ah[pab[mi] + aoff];
#pragma unroll
    for (int mi = 0; mi < 7; ++mi)
#pragma unroll
      for (int ni = 0; ni < 4; ++ni)
        acc[mi][ni] = __builtin_amdgcn_mfma_f32_16x16x32_bf16(
            af0[mi], bw[ni], acc[mi][ni], 0, 0, 0);
    bf16x8 af1[7];
#pragma unroll
    for (int mi = 0; mi < 7; ++mi)
      af1[mi] = *(const bf16x8*)&Ah[pab[mi] + aoff + 32];
#pragma unroll
    for (int mi = 0; mi < 7; ++mi)
#pragma unroll
      for (int ni = 0; ni < 4; ++ni)
        acc[mi][ni] = __builtin_amdgcn_mfma_f32_16x16x32_bf16(
            af1[mi], bw[4 + ni], acc[mi][ni], 0, 0, 0);
    if (t == 8 && kc + 1 < KC) {  // A window restage at kc boundary
      __syncthreads();
      stageA(kc + 1);
      __syncthreads();
    }
  };

  stageA(0);
  bf16x8 bwE[8], bwO[8];
  loadB(0, bwE);  // overlaps the A staging + barrier
  __syncthreads();

  const int NS = KC * 9;  // even (54 or 72)
#pragma unroll 1
  for (int s = 0; s < NS; s += 2) {
    loadB(s + 1, bwO);              // prefetch next step (hidden under MFMAs)
    compute(s, bwE);
    if (s + 2 < NS) loadB(s + 2, bwE);
    compute(s + 1, bwO);
  }

#pragma unroll
  for (int mi = 0; mi < 7; ++mi) {
#pragma unroll
    for (int r = 0; r < 4; ++r) {
      int idx = quad * 4 + r;            // M-row within tile, 0..15
      int wv = wm * 8 + (idx & 7);       // w' in 0..15
      if (wv == 0 || wv == 15) continue;  // dead column (halo)
      int hh = 1 + 2 * mi + (idx >> 3);  // h' in 1..14
      if (EPI == 0) {
        int cell = img * 256 + hh * 16 + wv;
        int slice = (n0 >> 6) + wn;
        size_t ob = ((size_t)slice * RA + cell) * 72 + tq;
#pragma unroll
        for (int ni = 0; ni < 4; ++ni)
          C[ob + ni * 16] = f2bf(fmaxf(acc[mi][ni][r], 0.f));
      } else {
        int p = (hh - 1) * 14 + (wv - 1);
        size_t ob = (size_t)(img * 196 + p) * 512 + n0 + wn * 64 + tq;
#pragma unroll
        for (int ni = 0; ni < 4; ++ni)
          C[ob + ni * 16] = f2bf(acc[mi][ni][r]);
      }
    }
  }
}

// ---------------------------------------------------------------------------
// gemm1_k: C[m,n] = sum_k A[m,k]*B[n,k]; 128x128 tile, 4 waves, BK=64,
// XOR-swizzled LDS. EPI: 0 relu->bf16, 2 f32, 3 f32 * rs[m] (row scale).
// ---------------------------------------------------------------------------
template <int K, int NLD, int EPI>
__global__ __launch_bounds__(256, 2) void gemm1_k(
    const unsigned short* __restrict__ A, const unsigned short* __restrict__ Bw,
    void* __restrict__ C, const float* __restrict__ rs) {
  __shared__ short As[128 * 64];
  __shared__ short Bs[128 * 64];
  const int tid = threadIdx.x;
  const int wave = tid >> 6, lane = tid & 63;
  const int m0 = blockIdx.x * 128, n0 = blockIdx.y * 128;
  const int rr8 = lane >> 3, seg = lane & 7, gseg = seg ^ rr8;
  const int wm = wave >> 1, wn = wave & 1;
  const int quad = lane >> 4, tq = lane & 15;

  size_t asrc[4], bsrc[4];
#pragma unroll
  for (int i8 = 0; i8 < 4; ++i8) {
    int rloc = wave * 32 + i8 * 8 + rr8;
    asrc[i8] = (size_t)(m0 + rloc) * K + gseg * 8;
    bsrc[i8] = (size_t)(n0 + rloc) * K + gseg * 8;
  }

  f32x4 acc[4][4];
#pragma unroll
  for (int mi = 0; mi < 4; ++mi)
#pragma unroll
    for (int ni = 0; ni < 4; ++ni) {
      f32x4 z = {0.f, 0.f, 0.f, 0.f};
      acc[mi][ni] = z;
    }

#pragma unroll 1
  for (int kc2 = 0; kc2 < K / 64; ++kc2) {
    int kb = kc2 * 64;
    __syncthreads();
#pragma unroll
    for (int i8 = 0; i8 < 4; ++i8) {
      gload_lds16(A + asrc[i8] + kb, &As[(wave * 32 + i8 * 8) * 64]);
      gload_lds16(Bw + bsrc[i8] + kb, &Bs[(wave * 32 + i8 * 8) * 64]);
    }
    __syncthreads();
#pragma unroll
    for (int h = 0; h < 2; ++h) {
      bf16x8 af[4], bfr[4];
#pragma unroll
      for (int mi = 0; mi < 4; ++mi) {
        int row = wm * 64 + mi * 16 + tq;
        af[mi] = *(const bf16x8*)&As[row * 64 +
                                     ((((h << 2) | quad) ^ (row & 7)) << 3)];
      }
#pragma unroll
      for (int ni = 0; ni < 4; ++ni) {
        int row = wn * 64 + ni * 16 + tq;
        bfr[ni] = *(const bf16x8*)&Bs[row * 64 +
                                      ((((h << 2) | quad) ^ (row & 7)) << 3)];
      }
#pragma unroll
      for (int mi = 0; mi < 4; ++mi)
#pragma unroll
        for (int ni = 0; ni < 4; ++ni)
          acc[mi][ni] = __builtin_amdgcn_mfma_f32_16x16x32_bf16(
              af[mi], bfr[ni], acc[mi][ni], 0, 0, 0);
    }
  }

#pragma unroll
  for (int mi = 0; mi < 4; ++mi) {
#pragma unroll
    for (int r = 0; r < 4; ++r) {
      int m = m0 + wm * 64 + mi * 16 + quad * 4 + r;
      float sc = (EPI == 3) ? rs[m] : 1.f;
      size_t obase = (size_t)m * NLD + n0 + wn * 64 + tq;
#pragma unroll
      for (int ni = 0; ni < 4; ++ni) {
        float v = acc[mi][ni][r];
        size_t idx = obase + ni * 16;
        if (EPI == 0)
          ((unsigned short*)C)[idx] = f2bf(fmaxf(v, 0.f));
        else if (EPI == 2)
          ((float*)C)[idx] = v;
        else
          ((float*)C)[idx] = v * sc;
      }
    }
  }
}

// Xm = (iv+eps).fa^T and Vm = indn.indn^T in one dispatch (blockIdx.z picks)
__global__ __launch_bounds__(256, 2) void gemm_xv_k(
    const unsigned short* __restrict__ ivpb, const unsigned short* __restrict__ fab,
    const unsigned short* __restrict__ indnb, float* __restrict__ Xm,
    float* __restrict__ Vm) {
  const unsigned short* A = blockIdx.z ? indnb : ivpb;
  const unsigned short* Bw = blockIdx.z ? indnb : fab;
  float* C = blockIdx.z ? Vm : Xm;
  __shared__ short As[128 * 64];
  __shared__ short Bs[128 * 64];
  const int tid = threadIdx.x;
  const int wave = tid >> 6, lane = tid & 63;
  const int m0 = blockIdx.x * 128, n0 = blockIdx.y * 128;
  const int rr8 = lane >> 3, seg = lane & 7, gseg = seg ^ rr8;
  const int wm = wave >> 1, wn = wave & 1;
  const int quad = lane >> 4, tq = lane & 15;
  size_t asrc[4], bsrc[4];
#pragma unroll
  for (int i8 = 0; i8 < 4; ++i8) {
    int rloc = wave * 32 + i8 * 8 + rr8;
    asrc[i8] = (size_t)(m0 + rloc) * 512 + gseg * 8;
    bsrc[i8] = (size_t)(n0 + rloc) * 512 + gseg * 8;
  }
  f32x4 acc[4][4];
#pragma unroll
  for (int mi = 0; mi < 4; ++mi)
#pragma unroll
    for (int ni = 0; ni < 4; ++ni) {
      f32x4 z = {0.f, 0.f, 0.f, 0.f};
      acc[mi][ni] = z;
    }
#pragma unroll 1
  for (int kc2 = 0; kc2 < 8; ++kc2) {
    int kb = kc2 * 64;
    __syncthreads();
#pragma unroll
    for (int i8 = 0; i8 < 4; ++i8) {
      gload_lds16(A + asrc[i8] + kb, &As[(wave * 32 + i8 * 8) * 64]);
      gload_lds16(Bw + bsrc[i8] + kb, &Bs[(wave * 32 + i8 * 8) * 64]);
    }
    __syncthreads();
#pragma unroll
    for (int h = 0; h < 2; ++h) {
      bf16x8 af[4], bfr[4];
#pragma unroll
      for (int mi = 0; mi < 4; ++mi) {
        int row = wm * 64 + mi * 16 + tq;
        af[mi] = *(const bf16x8*)&As[row * 64 +
                                     ((((h << 2) | quad) ^ (row & 7)) << 3)];
      }
#pragma unroll
      for (int ni = 0; ni < 4; ++ni) {
        int row = wn * 64 + ni * 16 + tq;
        bfr[ni] = *(const bf16x8*)&Bs[row * 64 +
                                      ((((h << 2) | quad) ^ (row & 7)) << 3)];
      }
#pragma unroll
      for (int mi = 0; mi < 4; ++mi)
#pragma unroll
        for (int ni = 0; ni < 4; ++ni)
          acc[mi][ni] = __builtin_amdgcn_mfma_f32_16x16x32_bf16(
              af[mi], bfr[ni], acc[mi][ni], 0, 0, 0);
    }
  }
#pragma unroll
  for (int mi = 0; mi < 4; ++mi)
#pragma unroll
    for (int r = 0; r < 4; ++r) {
      int m = m0 + wm * 64 + mi * 16 + quad * 4 + r;
      size_t obase = (size_t)m * 256 + n0 + wn * 64 + tq;
#pragma unroll
      for (int ni = 0; ni < 4; ++ni) C[obase + ni * 16] = acc[mi][ni][r];
    }
}

// --------------------------- prep (fused) ----------------------------------
// ranges: ea/Wf1/Wf2 casts | wb1 build | wb2 build | x1b halo zeroing
// wb layout (fragment-packed): flat index j =
//   (((t*KC+kc)*32 + g)*2 + h)*512 + quad*128 + tq*8 + jj
// value = Wc[n = g*16+tq][cin = kc*64 + h*32 + quad*8 + jj][tap t]
// -> writes are perfectly linear; the conv kernel reads 1KB coalesced spans.
__global__ void prep_all_k(const float* __restrict__ ea,
                           const float* __restrict__ Wf1,
                           const float* __restrict__ Wf2,
                           const float* __restrict__ Wc1,
                           const float* __restrict__ Wc2,
                           unsigned short* __restrict__ eab,
                           unsigned short* __restrict__ wf1b,
                           unsigned short* __restrict__ wf2b,
                           unsigned short* __restrict__ wb1,
                           unsigned short* __restrict__ wb2,
                           unsigned int* __restrict__ x1u) {
  int i = blockIdx.x * 256 + threadIdx.x;
  if (i < 524288) {
    eab[i] = f2bf(ea[i]);
  } else if (i < 1572864) {
    int j = i - 524288;
    wf1b[j] = f2bf(Wf1[j]);
  } else if (i < 1835008) {
    int j = i - 1572864;
    wf2b[j] = f2bf(Wf2[j]);
  } else if (i < 3604480) {
    int j = i - 1835008;  // wb1: 9*6*32768 fragment-packed <- Wc1[n][384][3][3]
    int t = j / (6 * 32768), r = j - t * (6 * 32768);
    int kc = r / 32768, r2 = r - kc * 32768;
    int g = r2 >> 10, h = (r2 >> 9) & 1, quad = (r2 >> 7) & 3;
    int tq = (r2 >> 3) & 15, jj = r2 & 7;
    int n = g * 16 + tq, cin = kc * 64 + h * 32 + quad * 8 + jj;
    wb1[j] = f2bf(Wc1[(n * 384 + cin) * 9 + t]);
  } else if (i < 5963776) {
    int j = i - 3604480;  // wb2: 9*8*32768 fragment-packed <- Wc2[n][512][3][3]
    int t = j / (8 * 32768), r = j - t * (8 * 32768);
    int kc = r / 32768, r2 = r - kc * 32768;
    int g = r2 >> 10, h = (r2 >> 9) & 1, quad = (r2 >> 7) & 3;
    int tq = (r2 >> 3) & 15, jj = r2 & 7;
    int n = g * 16 + tq, cin = kc * 64 + h * 32 + quad * 8 + jj;
    wb2[j] = f2bf(Wc2[(n * 512 + cin) * 9 + t]);
  } else {
    int j = i - 5963776;  // 15360 halo rows x 8 slices x 32 uints
    int hr = j >> 8, u = j & 255;
    int slice = u >> 5, uu = u & 31;
    int b = hr / 60, c = hr - b * 60;
    int cell;
    if (c < 16) cell = c;
    else if (c < 32) cell = 240 + (c - 16);
    else if (c < 46) cell = (c - 31) * 16;
    else cell = (c - 45) * 16 + 15;
    x1u[((size_t)slice * RA + b * 256 + cell) * 36 + uu] = 0u;
  }
}

// ev (256,384,14,14) fp32 -> evb [kc6][RA][72] bf16 (halo cells zero)
__global__ __launch_bounds__(256) void evpad_k(const float* __restrict__ ev,
                                               unsigned short* __restrict__ out) {
  int b = blockIdx.x, ct = blockIdx.y;  // channel tile: c0 = ct*64
  __shared__ float tile[64][197];
  int tid = threadIdx.x;
  const float* src = ev + ((size_t)b * 384 + ct * 64) * 196;
#pragma unroll 1
  for (int it = 0; it < 49; ++it) {
    int idx = it * 256 + tid;
    int c = idx / 196, p = idx - c * 196;
    tile[c][p] = src[idx];
  }
  __syncthreads();
  unsigned short* dst = out + ((size_t)ct * RA + b * 256) * 72;
#pragma unroll 1
  for (int it = 0; it < 64; ++it) {
    int idx = it * 256 + tid;
    int cell = idx >> 6, c = idx & 63;
    int h = (cell >> 4) - 1, w = (cell & 15) - 1;
    float v = ((unsigned)h < 14u && (unsigned)w < 14u) ? tile[c][h * 14 + w]
                                                       : 0.f;
    dst[(size_t)cell * 72 + c] = f2bf(v);
  }
}

// --------------------------- pooling / norms -------------------------------

// fused: masked mean pool + per-pixel inverse norm (rn) + ind normalization
__global__ __launch_bounds__(512) void pool_k(
    const unsigned short* __restrict__ fv, const int* __restrict__ masks,
    unsigned short* __restrict__ indnb, unsigned short* __restrict__ ivpb,
    float* __restrict__ Pi, float* __restrict__ rn) {
  int b = blockIdx.x;
  int w = threadIdx.x >> 6, lane = threadIdx.x & 63;
  __shared__ float red[8][512];
  __shared__ float msh[8];
  float acc[8] = {0.f, 0.f, 0.f, 0.f, 0.f, 0.f, 0.f, 0.f};
  float msum = 0.f;
  for (int p = w; p < 196; p += 8) {
    float m = (float)masks[b * 196 + p];
    msum += m;
    uint4 d = *(const uint4*)(fv + (size_t)(b * 196 + p) * 512 + lane * 8);
    const unsigned short* hp = (const unsigned short*)&d;
    float ss = 0.f;
#pragma unroll
    for (int k = 0; k < 8; ++k) {
      float x = bf2f(hp[k]);
      ss += x * x;
      acc[k] += m * x;
    }
    ss = waveSum(ss);
    if (lane == 0) rn[b * 196 + p] = 1.f / fmaxf(sqrtf(ss), 1e-12f);
  }
#pragma unroll
  for (int k = 0; k < 8; ++k) red[w][lane * 8 + k] = acc[k];
  if (lane == 0) msh[w] = msum;
  __syncthreads();
  int tid = threadIdx.x;
  float s = 0.f, mtot = 0.f;
#pragma unroll
  for (int ww = 0; ww < 8; ++ww) {
    s += red[ww][tid];
    mtot += msh[ww];
  }
  float v = s / mtot;  // indv[b, tid]
  float ss2 = blockSum<8>(v * v);
  float sc = 1.f / fmaxf(sqrtf(ss2), 1e-12f);
  indnb[b * 512 + tid] = f2bf(v * sc);
  float ve = v + 1e-6f;
  ivpb[b * 512 + tid] = f2bf(ve);
  float p2 = blockSum<8>(ve * ve);
  if (tid == 0) Pi[b] = p2;
}

// fa fp32 -> bf16 + Qj = ||fa_j||^2
__global__ __launch_bounds__(512) void fanorm_k(const float* __restrict__ fa,
                                                unsigned short* __restrict__ fab,
                                                float* __restrict__ Qj) {
  int b = blockIdx.x, tid = threadIdx.x;
  float v = fa[b * 512 + tid];
  fab[b * 512 + tid] = f2bf(v);
  float q = blockSum<8>(v * v);
  if (tid == 0) Qj[b] = q;
}

// ------------------------------ SP / SN ------------------------------------

__device__ __forceinline__ float radix_kth(unsigned k0, unsigned k1, unsigned k2,
                                           unsigned k3, int k) {
  unsigned prefix = 0;
  int kk = k;
#pragma unroll 1
  for (int bit = 31; bit >= 14; --bit) {  // 18 steps; thr err ~2^-9 rel, ok
    unsigned thi = (prefix >> bit) | 1u;
    int c = __popcll(__ballot((k0 >> bit) == thi)) +
            __popcll(__ballot((k1 >> bit) == thi)) +
            __popcll(__ballot((k2 >> bit) == thi)) +
            __popcll(__ballot((k3 >> bit) == thi));
    if (kk <= c)
      prefix |= (1u << bit);
    else
      kk -= c;
  }
  unsigned u = (prefix & 0x80000000u) ? (prefix ^ 0x80000000u) : ~prefix;
  return __uint_as_float(u);
}
__device__ __forceinline__ unsigned sortkey(float x) {
  unsigned u = __float_as_uint(x);
  return u ^ (((int)u >> 31) | 0x80000000u);
}

__global__ __launch_bounds__(256) void spsn_k(const float* __restrict__ Sij,
                                              float* __restrict__ SP,
                                              float* __restrict__ SN) {
  int i = blockIdx.x, jg = blockIdx.y;
  int tid = threadIdx.x, wave = tid >> 6, lane = tid & 63;
  __shared__ float tile[196 * 65];
#pragma unroll 1
  for (int it = 0; it < 49; ++it) {
    int lin = it * 256 + tid;
    int p = lin >> 6, j = lin & 63;
    tile[p * 65 + j] = Sij[(size_t)(i * 196 + p) * 256 + jg * 64 + j];
  }
  __syncthreads();
#pragma unroll 1
  for (int jj = 0; jj < 16; ++jj) {
    int j = jj * 4 + wave;
    float v0 = tile[lane * 65 + j];
    float v1 = tile[(lane + 64) * 65 + j];
    float v2 = tile[(lane + 128) * 65 + j];
    bool val3 = lane < 4;
    float v3 = val3 ? tile[(lane + 192) * 65 + j] : 0.f;
    unsigned k0 = sortkey(v0), k1 = sortkey(v1), k2 = sortkey(v2);
    unsigned k3 = val3 ? sortkey(v3) : 0u;
    float thrP = radix_kth(k0, k1, k2, k3, 19);
    float thrN = radix_kth(k0, k1, k2, k3, 99);
    float spn = 0.f, spd = 0.f, snn = 0.f, snd = 0.f;
    const float invTS = 1.f / 0.03f;
#pragma unroll
    for (int q = 0; q < 4; ++q) {
      float v = (q == 0) ? v0 : (q == 1) ? v1 : (q == 2) ? v2 : v3;
      bool ok = (q < 3) || val3;
      if (ok) {
        float mp = 1.f / (1.f + __expf((thrP - v) * invTS));
        float mn = 1.f / (1.f + __expf((v - thrN) * invTS));
        spn += v * mp;
        spd += mp;
        snn += v * mn;
        snd += mn;
      }
    }
    spn = waveSum(spn); spd = waveSum(spd);
    snn = waveSum(snn); snd = waveSum(snd);
    if (lane == 0) {
      SP[i * 256 + jg * 64 + j] = spn / spd;
      SN[i * 256 + jg * 64 + j] = snn / snd;
    }
  }
}

__global__ __launch_bounds__(256) void loss12_k(const float* __restrict__ SP,
                                                const float* __restrict__ SN,
                                                float* __restrict__ out) {
  int r = blockIdx.x;
  int i = r & 255;
  bool col = r >= 256;
  int tid = threadIdx.x;
  const float invTC = 1.f / 0.07f;
  float a = (col ? SP[tid * 256 + i] : SP[i * 256 + tid]) * invTC;
  float b = (col ? SN[tid * 256 + i] : SN[i * 256 + tid]) * invTC;
  float mx = blockMax<4>(fmaxf(a, b));
  float se = blockSum<4>(__expf(a - mx) + __expf(b - mx));
  float lse = mx + __logf(se);
  if (tid == 0) {
    float diag = SP[i * 256 + i] * invTC;
    atomicAdd(out, -(diag - lse) * (1.f / 512.f));
  }
}

__global__ __launch_bounds__(256) void distcomb_k(
    const float* __restrict__ Pi, const float* __restrict__ Qj,
    const float* __restrict__ X, const float* __restrict__ V,
    float* __restrict__ val, float* __restrict__ out) {
  int i = blockIdx.x, j = threadIdx.x;
  float d = Pi[i] - 2.f * X[i * 256 + j] + Qj[j];
  float w = (i == j) ? 1.f : -V[i * 256 + j];
  float x = d * w;
  val[i * 256 + j] = x;
  __shared__ float diag_sh;
  if (j == i) diag_sh = x;
  float tot = blockSum<4>(x);
  if (j == 0) {
    float rs = diag_sh - (tot - diag_sh) * (1.f / 255.f);
    atomicAdd(out + 1, fmaxf(rs + 0.6f, 0.f) * (1.f / 512.f));
  }
}

__global__ __launch_bounds__(256) void loss4_k(const float* __restrict__ val,
                                               float* __restrict__ out) {
  int j = blockIdx.x, i = threadIdx.x;
  float x = val[i * 256 + j];
  __shared__ float diag_sh;
  if (i == j) diag_sh = x;
  float tot = blockSum<4>(x);
  if (i == 0) {
    float cs = diag_sh - (tot - diag_sh) * (1.f / 255.f);
    atomicAdd(out + 1, fmaxf(cs + 0.6f, 0.f) * (1.f / 512.f));
  }
}

// ---------------------------------------------------------------------------

extern "C" void kernel_launch(void* const* d_in, const int* in_sizes, int n_in,
                              void* d_out, int out_size, void* d_ws,
                              size_t ws_size, hipStream_t stream) {
  (void)in_sizes; (void)n_in; (void)out_size; (void)ws_size;
  const float* ev = (const float*)d_in[0];
  const float* ea = (const float*)d_in[1];
  const int* msk = (const int*)d_in[2];
  const float* Wf1 = (const float*)d_in[3];
  const float* Wf2 = (const float*)d_in[4];
  const float* Wc1 = (const float*)d_in[5];
  const float* Wc2 = (const float*)d_in[6];
  float* out = (float*)d_out;
  char* ws = (char*)d_ws;

  size_t off = 0;
  auto alloc = [&](size_t bytes) {
    void* p = ws + off;
    off = (off + bytes + 255) & ~(size_t)255;
    return p;
  };
  // Region 1: max(evb 6*RA*144 = 56.6 MB ; fv 50176*512*2 = 51.4 MB)
  unsigned short* evb = (unsigned short*)alloc((size_t)6 * RA * 144);
  unsigned short* fv = evb;  // reused after conv2
  // Region 2: max(x1b 8*RA*144 = 75.5 MB ; Sij 50176*256*4 = 51.4 MB)
  unsigned short* x1b = (unsigned short*)alloc((size_t)8 * RA * 144);
  float* Sij = (float*)x1b;  // reused after conv2
  unsigned short* wb1 = (unsigned short*)alloc((size_t)9 * 6 * 32768 * 2);
  unsigned short* wb2 = (unsigned short*)alloc((size_t)9 * 8 * 32768 * 2);
  unsigned short* eab = (unsigned short*)alloc((size_t)256 * 2048 * 2);
  unsigned short* wf1b = (unsigned short*)alloc((size_t)512 * 2048 * 2);
  unsigned short* wf2b = (unsigned short*)alloc((size_t)512 * 512 * 2);
  unsigned short* hb = (unsigned short*)alloc((size_t)256 * 512 * 2);
  float* fa = (float*)alloc((size_t)256 * 512 * 4);
  unsigned short* indnb = (unsigned short*)alloc((size_t)256 * 512 * 2);
  unsigned short* ivpb = (unsigned short*)alloc((size_t)256 * 512 * 2);
  unsigned short* fab = (unsigned short*)alloc((size_t)256 * 512 * 2);
  float* Pi = (float*)alloc(256 * 4);
  float* Qj = (float*)alloc(256 * 4);
  float* Xm = (float*)alloc((size_t)256 * 256 * 4);
  float* Vm = (float*)alloc((size_t)256 * 256 * 4);
  float* rn = (float*)alloc((size_t)50176 * 4);
  float* SP = (float*)alloc((size_t)256 * 256 * 4);
  float* SN = (float*)alloc((size_t)256 * 256 * 4);
  float* val = (float*)alloc((size_t)256 * 256 * 4);

  hipMemsetAsync(out, 0, 2 * sizeof(float), stream);

  prep_all_k<<<38656, 256, 0, stream>>>(ea, Wf1, Wf2, Wc1, Wc2, eab, wf1b,
                                        wf2b, wb1, wb2, (unsigned int*)x1b);
  evpad_k<<<dim3(256, 6), 256, 0, stream>>>(ev, evb);

  // conv1: relu, cell rows k-major (one image per block, N=512, K=9*384)
  convtap6_k<6, 0><<<dim3(256, 4), 256, 0, stream>>>(evb, wb1, x1b);
  // fc1 / fc2
  gemm1_k<2048, 512, 0><<<dim3(2, 4), 256, 0, stream>>>(eab, wf1b, hb, nullptr);
  gemm1_k<512, 512, 2><<<dim3(2, 4), 256, 0, stream>>>(hb, wf2b, fa, nullptr);
  // conv2: compact bf16 out (one image per block, N=512, K=9*512)
  convtap6_k<8, 1><<<dim3(256, 4), 256, 0, stream>>>(x1b, wb2, fv);

  pool_k<<<256, 512, 0, stream>>>(fv, msk, indnb, ivpb, Pi, rn);
  fanorm_k<<<256, 512, 0, stream>>>(fa, fab, Qj);

  // Sij[(i,p), j] = rn[i,p] * <fv[i,p,:], indn[j,:]>  (M=50176, N=256, K=512)
  gemm1_k<512, 256, 3><<<dim3(392, 2), 256, 0, stream>>>(fv, indnb, Sij, rn);
  gemm_xv_k<<<dim3(2, 2, 2), 256, 0, stream>>>(ivpb, fab, indnb, Xm, Vm);

  spsn_k<<<dim3(256, 4), 256, 0, stream>>>(Sij, SP, SN);
  loss12_k<<<512, 256, 0, stream>>>(SP, SN, out);
  distcomb_k<<<256, 256, 0, stream>>>(Pi, Qj, Xm, Vm, val, out);
  loss4_k<<<256, 256, 0, stream>>>(val, out);
}

// Round 7
// 781.879 us; speedup vs baseline: 1.0748x; 1.0332x over previous
//
#include <hip/hip_runtime.h>
#include <stdint.h>

// ---------------------------------------------------------------------------
// B=256, H=W=14, HW=196, TS=0.03, TC=0.07, TP_K=19, TN_K=98
// Conv inputs: padded 16x16 cell grid per image (1-cell zero halo):
// cell = b*256 + (h+1)*16 + (w+1). Conv 3x3 = 9 cell-row shifts d=dh*16+dw.
// convtap6_k: block = ONE image (M padded 196->224 rows) x 128 N. The A
// window per kc is EXACTLY the image's 256 cell rows (36.9 KB) — covers all
// 9 taps incl. halo with no clamping, no cross-image span. acc 7x4/wave.
// M-tiling: each 16x16 MFMA tile = a 2x8 PIXEL BLOCK of the padded grid
// (tq -> dh=tq>>3, dw=tq&7; mi -> h-pair 1+2*mi; wm -> w-half) so the A-read
// bank-start residue 4*((tq&7)+quad) is uniform per quarter-wave, all taps.
// B PATH (R5 schedule, macro-expanded): weights in per-wave REGISTERS,
// fragment-packed (1KB coalesced span per (n-group,K-half)). Latency
// discipline — every load gets >=1 MFMA-cluster (~543 cyc) of cover:
//   - B h0 frags: double-buffered ONE STEP ahead (b0a/b0b, static names).
//   - B h1 frags: single buffer, loaded at TOP of the step, used after the
//     h0 cluster (~650 cyc later). Saves 16 regs vs full dbuf.
//   - A frags af0+af1 BOTH read before the h0 cluster: h1's LDS wait hides
//     behind h0's 28 MFMAs. (R2-R4 read af1 between clusters -> exposed.)
// Peak regs ~236 (acc 112 + af 56 + B 48 + addr) -> still 2 waves/SIMD.
// R0-R4 lesson: dur pinned at 245-250us while FETCH varied 2x and conflicts
// 2.3x -> conv is NOT memory/conflict-bound; it was exposed-latency-bound.
// Block mapping: DEFAULT (img=bx, n0=by*128): same-img blocks land on the
// same XCD (256≡0 mod 8) -> A stream XCD-local. (R4's weight-localizing
// remap scattered A 4x -> FETCH 170->195MB, no dur change. Reverted.)
// Grid 256x4 at 2 blocks/CU -> exactly 4 slots/CU, no tail quantization.
// NOTE: workspace regions are reused; size each by the MAX of its occupants.
// ---------------------------------------------------------------------------

typedef __attribute__((ext_vector_type(8))) short bf16x8;
typedef __attribute__((ext_vector_type(4))) float f32x4;

__device__ __forceinline__ unsigned short f2bf(float x) {
  unsigned u = __float_as_uint(x);
  unsigned r = u + 0x7FFFu + ((u >> 16) & 1u);  // RNE, no NaNs here
  return (unsigned short)(r >> 16);
}
__device__ __forceinline__ float bf2f(unsigned short h) {
  return __uint_as_float(((unsigned)h) << 16);
}

typedef const __attribute__((address_space(1))) void* gptr1_t;
typedef __attribute__((address_space(3))) void* lptr3_t;
__device__ __forceinline__ void gload_lds16(const void* g, void* l) {
  __builtin_amdgcn_global_load_lds((gptr1_t)g, (lptr3_t)l, 16, 0, 0);
}

__device__ __forceinline__ float waveSum(float v) {
#pragma unroll
  for (int m = 1; m < 64; m <<= 1) v += __shfl_xor(v, m, 64);
  return v;
}
__device__ __forceinline__ float waveMax(float v) {
#pragma unroll
  for (int m = 1; m < 64; m <<= 1) v = fmaxf(v, __shfl_xor(v, m, 64));
  return v;
}
template <int NW>
__device__ __forceinline__ float blockSum(float v) {
  __shared__ float sh[NW];
  v = waveSum(v);
  int wv = threadIdx.x >> 6, ln = threadIdx.x & 63;
  if (ln == 0) sh[wv] = v;
  __syncthreads();
  float r = 0.f;
#pragma unroll
  for (int w = 0; w < NW; ++w) r += sh[w];
  __syncthreads();
  return r;
}
template <int NW>
__device__ __forceinline__ float blockMax(float v) {
  __shared__ float sh[NW];
  v = waveMax(v);
  int wv = threadIdx.x >> 6, ln = threadIdx.x & 63;
  if (ln == 0) sh[wv] = v;
  __syncthreads();
  float r = -3.4e38f;
#pragma unroll
  for (int w = 0; w < NW; ++w) r = fmaxf(r, sh[w]);
  __syncthreads();
  return r;
}

#define RA 65536  // rows per k-slice of conv input buffers

// ---------------------------------------------------------------------------
// convtap6_k: one image per block-x. C[p,n] = sum_t sum_k A[cell(p)+d_t,k]B[t,n,k]
// 256 thr, 4 waves (wm in {0,1}: w-half, wn in {0,1}: 64 cols), acc 7x4 of
// 16x16x32 bf16 MFMA. A: [kc][RA][72] shorts (LDS window 256x72 = 36.9 KB).
// B: fragment-packed [t][kc][g(32)][h(2)][lane(64)][8] shorts, reg-loaded.
// EPI 0: relu -> x1b (cell rows, k-major slices). EPI 1: bf16 -> fv compact.
// ---------------------------------------------------------------------------
template <int KC, int EPI>
__global__ __launch_bounds__(256, 2) void convtap6_k(
    const unsigned short* __restrict__ A, const unsigned short* __restrict__ Bw,
    unsigned short* __restrict__ C) {
  __shared__ __align__(16) short Ah[256 * 72];
  const int tid = threadIdx.x;
  const int wave = tid >> 6, lane = tid & 63;
  const int wm = wave >> 1, wn = wave & 1;
  const int quad = lane >> 4, tq = lane & 15;
  const int img = blockIdx.x, n0 = blockIdx.y * 128;

  // A-row per MFMA tile: tile = 2x8 pixel block; lane tq -> (dh, dw).
  int pab[7];
  {
    const int dh = tq >> 3;
    int wq = wm * 8 + (tq & 7);          // w' in 0..15
    if (wq == 0) wq = 8;                 // dead col -> mirrored valid col,
    else if (wq == 15) wq = 7;           // same bank residue, taps in-bounds
#pragma unroll
    for (int mi = 0; mi < 7; ++mi) {
      int pr = (1 + 2 * mi + dh) * 16 + wq;  // h' in 1..14
      pab[mi] = pr * 72 + quad * 8;
    }
  }
  // B fragment base (16B units): (t*KC+kc)*4096 + g*128 + h*64 + lane
  const int gb = (n0 >> 4) + wn * 4;

  const char* Ab = (const char*)A;
  const int l16 = lane * 16;

  f32x4 acc[7][4];
#pragma unroll
  for (int mi = 0; mi < 7; ++mi)
#pragma unroll
    for (int ni = 0; ni < 4; ++ni) {
      f32x4 z = {0.f, 0.f, 0.f, 0.f};
      acc[mi][ni] = z;
    }

  auto stageA = [&](int kc) {
    size_t s0 = ((size_t)kc * RA + img * 256) * 144;
#pragma unroll
    for (int i = 0; i < 9; ++i) {
      int c = wave + i * 4;  // 36 chunks of 1024 B
      gload_lds16(Ab + s0 + (size_t)c * 1024 + l16, (char*)Ah + c * 1024);
    }
  };

  const int NS = KC * 9;  // even (54 or 72)

  stageA(0);
  bf16x8 b0a[4], b0b[4], b1[4];
  {  // h0 fragments of step 0 (t=0, kc=0): overlaps A staging + barrier
    const int base0 = gb * 128 + lane;
#pragma unroll
    for (int ni = 0; ni < 4; ++ni)
      b0a[ni] = *(const bf16x8*)&Bw[(size_t)(base0 + ni * 128) * 8];
  }
  __syncthreads();

// One K-step: h1 load (used ~650cyc later) -> h0-of-next prefetch (used a
// full step later) -> af0+af1 ds_reads -> h0 MFMA cluster -> h1 MFMA
// cluster -> A restage at kc boundary. B0CUR/B0NXT are static array names.
#define CONV_STEP(SS, B0CUR, B0NXT, DO_PREF)                               \
  {                                                                        \
    const int kc_ = (SS) / 9, t_ = (SS) - kc_ * 9;                         \
    const int base_ = (t_ * KC + kc_) * 4096 + gb * 128 + lane;            \
    _Pragma("unroll")                                                      \
    for (int ni = 0; ni < 4; ++ni)                                         \
      b1[ni] = *(const bf16x8*)&Bw[(size_t)(base_ + ni * 128 + 64) * 8];   \
    if (DO_PREF) {                                                         \
      const int s1_ = (SS) + 1;                                            \
      const int kc1_ = s1_ / 9, t1_ = s1_ - kc1_ * 9;                      \
      const int bb_ = (t1_ * KC + kc1_) * 4096 + gb * 128 + lane;          \
      _Pragma("unroll")                                                    \
      for (int ni = 0; ni < 4; ++ni)                                       \
        B0NXT[ni] = *(const bf16x8*)&Bw[(size_t)(bb_ + ni * 128) * 8];     \
    }                                                                      \
    const int aoff_ = (((t_ / 3) - 1) * 16 + (t_ % 3) - 1) * 72;           \
    bf16x8 af0_[7], af1_[7];                                               \
    _Pragma("unroll")                                                      \
    for (int mi = 0; mi < 7; ++mi)                                         \
      af0_[mi] = *(const bf16x8*)&Ah[pab[mi] + aoff_];                     \
    _Pragma("unroll")                                                      \
    for (int mi = 0; mi < 7; ++mi)                                         \
      af1_[mi] = *(const bf16x8*)&Ah[pab[mi] + aoff_ + 32];                \
    _Pragma("unroll")                                                      \
    for (int mi = 0; mi < 7; ++mi) {                                       \
      _Pragma("unroll")                                                    \
      for (int ni = 0; ni < 4; ++ni)                                       \
        acc[mi][ni] = __builtin_amdgcn_mfma_f32_16x16x32_bf16(             \
            af0_[mi], B0CUR[ni], acc[mi][ni], 0, 0, 0);                    \
    }                                                                      \
    _Pragma("unroll")                                                      \
    for (int mi = 0; mi < 7; ++mi) {                                       \
      _Pragma("unroll")                                                    \
      for (int ni = 0; ni < 4; ++ni)                                       \
        acc[mi][ni] = __builtin_amdgcn_mfma_f32_16x16x32_bf16(             \
            af1_[mi], b1[ni], acc[mi][ni], 0, 0, 0);                       \
    }                                                                      \
    if (t_ == 8 && kc_ + 1 < KC) {                                         \
      __syncthreads();                                                     \
      stageA(kc_ + 1);                                                     \
      __syncthreads();                                                     \
    }                                                                      \
  }

#pragma unroll 1
  for (int s = 0; s < NS; s += 2) {
    CONV_STEP(s, b0a, b0b, true);
    CONV_STEP(s + 1, b0b, b0a, (s + 2 < NS));
  }
#undef CONV_STEP

#pragma unroll
  for (int mi = 0; mi < 7; ++mi) {
#pragma unroll
    for (int r = 0; r < 4; ++r) {
      int idx = quad * 4 + r;            // M-row within tile, 0..15
      int wv = wm * 8 + (idx & 7);       // w' in 0..15
      if (wv == 0 || wv == 15) continue;  // dead column (halo)
      int hh = 1 + 2 * mi + (idx >> 3);  // h' in 1..14
      if (EPI == 0) {
        int cell = img * 256 + hh * 16 + wv;
        int slice = (n0 >> 6) + wn;
        size_t ob = ((size_t)slice * RA + cell) * 72 + tq;
#pragma unroll
        for (int ni = 0; ni < 4; ++ni)
          C[ob + ni * 16] = f2bf(fmaxf(acc[mi][ni][r], 0.f));
      } else {
        int p = (hh - 1) * 14 + (wv - 1);
        size_t ob = (size_t)(img * 196 + p) * 512 + n0 + wn * 64 + tq;
#pragma unroll
        for (int ni = 0; ni < 4; ++ni)
          C[ob + ni * 16] = f2bf(acc[mi][ni][r]);
      }
    }
  }
}

// ---------------------------------------------------------------------------
// gemm1_k: C[m,n] = sum_k A[m,k]*B[n,k]; 128x128 tile, 4 waves, BK=64,
// XOR-swizzled LDS. EPI: 0 relu->bf16, 2 f32, 3 f32 * rs[m] (row scale).
// ---------------------------------------------------------------------------
template <int K, int NLD, int EPI>
__global__ __launch_bounds__(256, 2) void gemm1_k(
    const unsigned short* __restrict__ A, const unsigned short* __restrict__ Bw,
    void* __restrict__ C, const float* __restrict__ rs) {
  __shared__ short As[128 * 64];
  __shared__ short Bs[128 * 64];
  const int tid = threadIdx.x;
  const int wave = tid >> 6, lane = tid & 63;
  const int m0 = blockIdx.x * 128, n0 = blockIdx.y * 128;
  const int rr8 = lane >> 3, seg = lane & 7, gseg = seg ^ rr8;
  const int wm = wave >> 1, wn = wave & 1;
  const int quad = lane >> 4, tq = lane & 15;

  size_t asrc[4], bsrc[4];
#pragma unroll
  for (int i8 = 0; i8 < 4; ++i8) {
    int rloc = wave * 32 + i8 * 8 + rr8;
    asrc[i8] = (size_t)(m0 + rloc) * K + gseg * 8;
    bsrc[i8] = (size_t)(n0 + rloc) * K + gseg * 8;
  }

  f32x4 acc[4][4];
#pragma unroll
  for (int mi = 0; mi < 4; ++mi)
#pragma unroll
    for (int ni = 0; ni < 4; ++ni) {
      f32x4 z = {0.f, 0.f, 0.f, 0.f};
      acc[mi][ni] = z;
    }

#pragma unroll 1
  for (int kc2 = 0; kc2 < K / 64; ++kc2) {
    int kb = kc2 * 64;
    __syncthreads();
#pragma unroll
    for (int i8 = 0; i8 < 4; ++i8) {
      gload_lds16(A + asrc[i8] + kb, &As[(wave * 32 + i8 * 8) * 64]);
      gload_lds16(Bw + bsrc[i8] + kb, &Bs[(wave * 32 + i8 * 8) * 64]);
    }
    __syncthreads();
#pragma unroll
    for (int h = 0; h < 2; ++h) {
      bf16x8 af[4], bfr[4];
#pragma unroll
      for (int mi = 0; mi < 4; ++mi) {
        int row = wm * 64 + mi * 16 + tq;
        af[mi] = *(const bf16x8*)&As[row * 64 +
                                     ((((h << 2) | quad) ^ (row & 7)) << 3)];
      }
#pragma unroll
      for (int ni = 0; ni < 4; ++ni) {
        int row = wn * 64 + ni * 16 + tq;
        bfr[ni] = *(const bf16x8*)&Bs[row * 64 +
                                      ((((h << 2) | quad) ^ (row & 7)) << 3)];
      }
#pragma unroll
      for (int mi = 0; mi < 4; ++mi)
#pragma unroll
        for (int ni = 0; ni < 4; ++ni)
          acc[mi][ni] = __builtin_amdgcn_mfma_f32_16x16x32_bf16(
              af[mi], bfr[ni], acc[mi][ni], 0, 0, 0);
    }
  }

#pragma unroll
  for (int mi = 0; mi < 4; ++mi) {
#pragma unroll
    for (int r = 0; r < 4; ++r) {
      int m = m0 + wm * 64 + mi * 16 + quad * 4 + r;
      float sc = (EPI == 3) ? rs[m] : 1.f;
      size_t obase = (size_t)m * NLD + n0 + wn * 64 + tq;
#pragma unroll
      for (int ni = 0; ni < 4; ++ni) {
        float v = acc[mi][ni][r];
        size_t idx = obase + ni * 16;
        if (EPI == 0)
          ((unsigned short*)C)[idx] = f2bf(fmaxf(v, 0.f));
        else if (EPI == 2)
          ((float*)C)[idx] = v;
        else
          ((float*)C)[idx] = v * sc;
      }
    }
  }
}

// Xm = (iv+eps).fa^T and Vm = indn.indn^T in one dispatch (blockIdx.z picks)
__global__ __launch_bounds__(256, 2) void gemm_xv_k(
    const unsigned short* __restrict__ ivpb, const unsigned short* __restrict__ fab,
    const unsigned short* __restrict__ indnb, float* __restrict__ Xm,
    float* __restrict__ Vm) {
  const unsigned short* A = blockIdx.z ? indnb : ivpb;
  const unsigned short* Bw = blockIdx.z ? indnb : fab;
  float* C = blockIdx.z ? Vm : Xm;
  __shared__ short As[128 * 64];
  __shared__ short Bs[128 * 64];
  const int tid = threadIdx.x;
  const int wave = tid >> 6, lane = tid & 63;
  const int m0 = blockIdx.x * 128, n0 = blockIdx.y * 128;
  const int rr8 = lane >> 3, seg = lane & 7, gseg = seg ^ rr8;
  const int wm = wave >> 1, wn = wave & 1;
  const int quad = lane >> 4, tq = lane & 15;
  size_t asrc[4], bsrc[4];
#pragma unroll
  for (int i8 = 0; i8 < 4; ++i8) {
    int rloc = wave * 32 + i8 * 8 + rr8;
    asrc[i8] = (size_t)(m0 + rloc) * 512 + gseg * 8;
    bsrc[i8] = (size_t)(n0 + rloc) * 512 + gseg * 8;
  }
  f32x4 acc[4][4];
#pragma unroll
  for (int mi = 0; mi < 4; ++mi)
#pragma unroll
    for (int ni = 0; ni < 4; ++ni) {
      f32x4 z = {0.f, 0.f, 0.f, 0.f};
      acc[mi][ni] = z;
    }
#pragma unroll 1
  for (int kc2 = 0; kc2 < 8; ++kc2) {
    int kb = kc2 * 64;
    __syncthreads();
#pragma unroll
    for (int i8 = 0; i8 < 4; ++i8) {
      gload_lds16(A + asrc[i8] + kb, &As[(wave * 32 + i8 * 8) * 64]);
      gload_lds16(Bw + bsrc[i8] + kb, &Bs[(wave * 32 + i8 * 8) * 64]);
    }
    __syncthreads();
#pragma unroll
    for (int h = 0; h < 2; ++h) {
      bf16x8 af[4], bfr[4];
#pragma unroll
      for (int mi = 0; mi < 4; ++mi) {
        int row = wm * 64 + mi * 16 + tq;
        af[mi] = *(const bf16x8*)&As[row * 64 +
                                     ((((h << 2) | quad) ^ (row & 7)) << 3)];
      }
#pragma unroll
      for (int ni = 0; ni < 4; ++ni) {
        int row = wn * 64 + ni * 16 + tq;
        bfr[ni] = *(const bf16x8*)&Bs[row * 64 +
                                      ((((h << 2) | quad) ^ (row & 7)) << 3)];
      }
#pragma unroll
      for (int mi = 0; mi < 4; ++mi)
#pragma unroll
        for (int ni = 0; ni < 4; ++ni)
          acc[mi][ni] = __builtin_amdgcn_mfma_f32_16x16x32_bf16(
              af[mi], bfr[ni], acc[mi][ni], 0, 0, 0);
    }
  }
#pragma unroll
  for (int mi = 0; mi < 4; ++mi)
#pragma unroll
    for (int r = 0; r < 4; ++r) {
      int m = m0 + wm * 64 + mi * 16 + quad * 4 + r;
      size_t obase = (size_t)m * 256 + n0 + wn * 64 + tq;
#pragma unroll
      for (int ni = 0; ni < 4; ++ni) C[obase + ni * 16] = acc[mi][ni][r];
    }
}

// --------------------------- prep (fused) ----------------------------------
// ranges: ea/Wf1/Wf2 casts | wb1 build | wb2 build | x1b halo zeroing
// wb layout (fragment-packed): flat index j =
//   (((t*KC+kc)*32 + g)*2 + h)*512 + quad*128 + tq*8 + jj
// value = Wc[n = g*16+tq][cin = kc*64 + h*32 + quad*8 + jj][tap t]
// -> writes are perfectly linear; the conv kernel reads 1KB coalesced spans.
__global__ void prep_all_k(const float* __restrict__ ea,
                           const float* __restrict__ Wf1,
                           const float* __restrict__ Wf2,
                           const float* __restrict__ Wc1,
                           const float* __restrict__ Wc2,
                           unsigned short* __restrict__ eab,
                           unsigned short* __restrict__ wf1b,
                           unsigned short* __restrict__ wf2b,
                           unsigned short* __restrict__ wb1,
                           unsigned short* __restrict__ wb2,
                           unsigned int* __restrict__ x1u) {
  int i = blockIdx.x * 256 + threadIdx.x;
  if (i < 524288) {
    eab[i] = f2bf(ea[i]);
  } else if (i < 1572864) {
    int j = i - 524288;
    wf1b[j] = f2bf(Wf1[j]);
  } else if (i < 1835008) {
    int j = i - 1572864;
    wf2b[j] = f2bf(Wf2[j]);
  } else if (i < 3604480) {
    int j = i - 1835008;  // wb1: 9*6*32768 fragment-packed <- Wc1[n][384][3][3]
    int t = j / (6 * 32768), r = j - t * (6 * 32768);
    int kc = r / 32768, r2 = r - kc * 32768;
    int g = r2 >> 10, h = (r2 >> 9) & 1, quad = (r2 >> 7) & 3;
    int tq = (r2 >> 3) & 15, jj = r2 & 7;
    int n = g * 16 + tq, cin = kc * 64 + h * 32 + quad * 8 + jj;
    wb1[j] = f2bf(Wc1[(n * 384 + cin) * 9 + t]);
  } else if (i < 5963776) {
    int j = i - 3604480;  // wb2: 9*8*32768 fragment-packed <- Wc2[n][512][3][3]
    int t = j / (8 * 32768), r = j - t * (8 * 32768);
    int kc = r / 32768, r2 = r - kc * 32768;
    int g = r2 >> 10, h = (r2 >> 9) & 1, quad = (r2 >> 7) & 3;
    int tq = (r2 >> 3) & 15, jj = r2 & 7;
    int n = g * 16 + tq, cin = kc * 64 + h * 32 + quad * 8 + jj;
    wb2[j] = f2bf(Wc2[(n * 512 + cin) * 9 + t]);
  } else {
    int j = i - 5963776;  // 15360 halo rows x 8 slices x 32 uints
    int hr = j >> 8, u = j & 255;
    int slice = u >> 5, uu = u & 31;
    int b = hr / 60, c = hr - b * 60;
    int cell;
    if (c < 16) cell = c;
    else if (c < 32) cell = 240 + (c - 16);
    else if (c < 46) cell = (c - 31) * 16;
    else cell = (c - 45) * 16 + 15;
    x1u[((size_t)slice * RA + b * 256 + cell) * 36 + uu] = 0u;
  }
}

// ev (256,384,14,14) fp32 -> evb [kc6][RA][72] bf16 (halo cells zero)
__global__ __launch_bounds__(256) void evpad_k(const float* __restrict__ ev,
                                               unsigned short* __restrict__ out) {
  int b = blockIdx.x, ct = blockIdx.y;  // channel tile: c0 = ct*64
  __shared__ float tile[64][197];
  int tid = threadIdx.x;
  const float* src = ev + ((size_t)b * 384 + ct * 64) * 196;
#pragma unroll 1
  for (int it = 0; it < 49; ++it) {
    int idx = it * 256 + tid;
    int c = idx / 196, p = idx - c * 196;
    tile[c][p] = src[idx];
  }
  __syncthreads();
  unsigned short* dst = out + ((size_t)ct * RA + b * 256) * 72;
#pragma unroll 1
  for (int it = 0; it < 64; ++it) {
    int idx = it * 256 + tid;
    int cell = idx >> 6, c = idx & 63;
    int h = (cell >> 4) - 1, w = (cell & 15) - 1;
    float v = ((unsigned)h < 14u && (unsigned)w < 14u) ? tile[c][h * 14 + w]
                                                       : 0.f;
    dst[(size_t)cell * 72 + c] = f2bf(v);
  }
}

// --------------------------- pooling / norms -------------------------------

// fused: masked mean pool + per-pixel inverse norm (rn) + ind normalization
__global__ __launch_bounds__(512) void pool_k(
    const unsigned short* __restrict__ fv, const int* __restrict__ masks,
    unsigned short* __restrict__ indnb, unsigned short* __restrict__ ivpb,
    float* __restrict__ Pi, float* __restrict__ rn) {
  int b = blockIdx.x;
  int w = threadIdx.x >> 6, lane = threadIdx.x & 63;
  __shared__ float red[8][512];
  __shared__ float msh[8];
  float acc[8] = {0.f, 0.f, 0.f, 0.f, 0.f, 0.f, 0.f, 0.f};
  float msum = 0.f;
  for (int p = w; p < 196; p += 8) {
    float m = (float)masks[b * 196 + p];
    msum += m;
    uint4 d = *(const uint4*)(fv + (size_t)(b * 196 + p) * 512 + lane * 8);
    const unsigned short* hp = (const unsigned short*)&d;
    float ss = 0.f;
#pragma unroll
    for (int k = 0; k < 8; ++k) {
      float x = bf2f(hp[k]);
      ss += x * x;
      acc[k] += m * x;
    }
    ss = waveSum(ss);
    if (lane == 0) rn[b * 196 + p] = 1.f / fmaxf(sqrtf(ss), 1e-12f);
  }
#pragma unroll
  for (int k = 0; k < 8; ++k) red[w][lane * 8 + k] = acc[k];
  if (lane == 0) msh[w] = msum;
  __syncthreads();
  int tid = threadIdx.x;
  float s = 0.f, mtot = 0.f;
#pragma unroll
  for (int ww = 0; ww < 8; ++ww) {
    s += red[ww][tid];
    mtot += msh[ww];
  }
  float v = s / mtot;  // indv[b, tid]
  float ss2 = blockSum<8>(v * v);
  float sc = 1.f / fmaxf(sqrtf(ss2), 1e-12f);
  indnb[b * 512 + tid] = f2bf(v * sc);
  float ve = v + 1e-6f;
  ivpb[b * 512 + tid] = f2bf(ve);
  float p2 = blockSum<8>(ve * ve);
  if (tid == 0) Pi[b] = p2;
}

// fa fp32 -> bf16 + Qj = ||fa_j||^2
__global__ __launch_bounds__(512) void fanorm_k(const float* __restrict__ fa,
                                                unsigned short* __restrict__ fab,
                                                float* __restrict__ Qj) {
  int b = blockIdx.x, tid = threadIdx.x;
  float v = fa[b * 512 + tid];
  fab[b * 512 + tid] = f2bf(v);
  float q = blockSum<8>(v * v);
  if (tid == 0) Qj[b] = q;
}

// ------------------------------ SP / SN ------------------------------------

__device__ __forceinline__ float radix_kth(unsigned k0, unsigned k1, unsigned k2,
                                           unsigned k3, int k) {
  unsigned prefix = 0;
  int kk = k;
#pragma unroll 1
  for (int bit = 31; bit >= 14; --bit) {  // 18 steps; thr err ~2^-9 rel, ok
    unsigned thi = (prefix >> bit) | 1u;
    int c = __popcll(__ballot((k0 >> bit) == thi)) +
            __popcll(__ballot((k1 >> bit) == thi)) +
            __popcll(__ballot((k2 >> bit) == thi)) +
            __popcll(__ballot((k3 >> bit) == thi));
    if (kk <= c)
      prefix |= (1u << bit);
    else
      kk -= c;
  }
  unsigned u = (prefix & 0x80000000u) ? (prefix ^ 0x80000000u) : ~prefix;
  return __uint_as_float(u);
}
__device__ __forceinline__ unsigned sortkey(float x) {
  unsigned u = __float_as_uint(x);
  return u ^ (((int)u >> 31) | 0x80000000u);
}

__global__ __launch_bounds__(256) void spsn_k(const float* __restrict__ Sij,
                                              float* __restrict__ SP,
                                              float* __restrict__ SN) {
  int i = blockIdx.x, jg = blockIdx.y;
  int tid = threadIdx.x, wave = tid >> 6, lane = tid & 63;
  __shared__ float tile[196 * 65];
#pragma unroll 1
  for (int it = 0; it < 49; ++it) {
    int lin = it * 256 + tid;
    int p = lin >> 6, j = lin & 63;
    tile[p * 65 + j] = Sij[(size_t)(i * 196 + p) * 256 + jg * 64 + j];
  }
  __syncthreads();
#pragma unroll 1
  for (int jj = 0; jj < 16; ++jj) {
    int j = jj * 4 + wave;
    float v0 = tile[lane * 65 + j];
    float v1 = tile[(lane + 64) * 65 + j];
    float v2 = tile[(lane + 128) * 65 + j];
    bool val3 = lane < 4;
    float v3 = val3 ? tile[(lane + 192) * 65 + j] : 0.f;
    unsigned k0 = sortkey(v0), k1 = sortkey(v1), k2 = sortkey(v2);
    unsigned k3 = val3 ? sortkey(v3) : 0u;
    float thrP = radix_kth(k0, k1, k2, k3, 19);
    float thrN = radix_kth(k0, k1, k2, k3, 99);
    float spn = 0.f, spd = 0.f, snn = 0.f, snd = 0.f;
    const float invTS = 1.f / 0.03f;
#pragma unroll
    for (int q = 0; q < 4; ++q) {
      float v = (q == 0) ? v0 : (q == 1) ? v1 : (q == 2) ? v2 : v3;
      bool ok = (q < 3) || val3;
      if (ok) {
        float mp = 1.f / (1.f + __expf((thrP - v) * invTS));
        float mn = 1.f / (1.f + __expf((v - thrN) * invTS));
        spn += v * mp;
        spd += mp;
        snn += v * mn;
        snd += mn;
      }
    }
    spn = waveSum(spn); spd = waveSum(spd);
    snn = waveSum(snn); snd = waveSum(snd);
    if (lane == 0) {
      SP[i * 256 + jg * 64 + j] = spn / spd;
      SN[i * 256 + jg * 64 + j] = snn / snd;
    }
  }
}

__global__ __launch_bounds__(256) void loss12_k(const float* __restrict__ SP,
                                                const float* __restrict__ SN,
                                                float* __restrict__ out) {
  int r = blockIdx.x;
  int i = r & 255;
  bool col = r >= 256;
  int tid = threadIdx.x;
  const float invTC = 1.f / 0.07f;
  float a = (col ? SP[tid * 256 + i] : SP[i * 256 + tid]) * invTC;
  float b = (col ? SN[tid * 256 + i] : SN[i * 256 + tid]) * invTC;
  float mx = blockMax<4>(fmaxf(a, b));
  float se = blockSum<4>(__expf(a - mx) + __expf(b - mx));
  float lse = mx + __logf(se);
  if (tid == 0) {
    float diag = SP[i * 256 + i] * invTC;
    atomicAdd(out, -(diag - lse) * (1.f / 512.f));
  }
}

__global__ __launch_bounds__(256) void distcomb_k(
    const float* __restrict__ Pi, const float* __restrict__ Qj,
    const float* __restrict__ X, const float* __restrict__ V,
    float* __restrict__ val, float* __restrict__ out) {
  int i = blockIdx.x, j = threadIdx.x;
  float d = Pi[i] - 2.f * X[i * 256 + j] + Qj[j];
  float w = (i == j) ? 1.f : -V[i * 256 + j];
  float x = d * w;
  val[i * 256 + j] = x;
  __shared__ float diag_sh;
  if (j == i) diag_sh = x;
  float tot = blockSum<4>(x);
  if (j == 0) {
    float rs = diag_sh - (tot - diag_sh) * (1.f / 255.f);
    atomicAdd(out + 1, fmaxf(rs + 0.6f, 0.f) * (1.f / 512.f));
  }
}

__global__ __launch_bounds__(256) void loss4_k(const float* __restrict__ val,
                                               float* __restrict__ out) {
  int j = blockIdx.x, i = threadIdx.x;
  float x = val[i * 256 + j];
  __shared__ float diag_sh;
  if (i == j) diag_sh = x;
  float tot = blockSum<4>(x);
  if (i == 0) {
    float cs = diag_sh - (tot - diag_sh) * (1.f / 255.f);
    atomicAdd(out + 1, fmaxf(cs + 0.6f, 0.f) * (1.f / 512.f));
  }
}

// ---------------------------------------------------------------------------

extern "C" void kernel_launch(void* const* d_in, const int* in_sizes, int n_in,
                              void* d_out, int out_size, void* d_ws,
                              size_t ws_size, hipStream_t stream) {
  (void)in_sizes; (void)n_in; (void)out_size; (void)ws_size;
  const float* ev = (const float*)d_in[0];
  const float* ea = (const float*)d_in[1];
  const int* msk = (const int*)d_in[2];
  const float* Wf1 = (const float*)d_in[3];
  const float* Wf2 = (const float*)d_in[4];
  const float* Wc1 = (const float*)d_in[5];
  const float* Wc2 = (const float*)d_in[6];
  float* out = (float*)d_out;
  char* ws = (char*)d_ws;

  size_t off = 0;
  auto alloc = [&](size_t bytes) {
    void* p = ws + off;
    off = (off + bytes + 255) & ~(size_t)255;
    return p;
  };
  // Region 1: max(evb 6*RA*144 = 56.6 MB ; fv 50176*512*2 = 51.4 MB)
  unsigned short* evb = (unsigned short*)alloc((size_t)6 * RA * 144);
  unsigned short* fv = evb;  // reused after conv2
  // Region 2: max(x1b 8*RA*144 = 75.5 MB ; Sij 50176*256*4 = 51.4 MB)
  unsigned short* x1b = (unsigned short*)alloc((size_t)8 * RA * 144);
  float* Sij = (float*)x1b;  // reused after conv2
  unsigned short* wb1 = (unsigned short*)alloc((size_t)9 * 6 * 32768 * 2);
  unsigned short* wb2 = (unsigned short*)alloc((size_t)9 * 8 * 32768 * 2);
  unsigned short* eab = (unsigned short*)alloc((size_t)256 * 2048 * 2);
  unsigned short* wf1b = (unsigned short*)alloc((size_t)512 * 2048 * 2);
  unsigned short* wf2b = (unsigned short*)alloc((size_t)512 * 512 * 2);
  unsigned short* hb = (unsigned short*)alloc((size_t)256 * 512 * 2);
  float* fa = (float*)alloc((size_t)256 * 512 * 4);
  unsigned short* indnb = (unsigned short*)alloc((size_t)256 * 512 * 2);
  unsigned short* ivpb = (unsigned short*)alloc((size_t)256 * 512 * 2);
  unsigned short* fab = (unsigned short*)alloc((size_t)256 * 512 * 2);
  float* Pi = (float*)alloc(256 * 4);
  float* Qj = (float*)alloc(256 * 4);
  float* Xm = (float*)alloc((size_t)256 * 256 * 4);
  float* Vm = (float*)alloc((size_t)256 * 256 * 4);
  float* rn = (float*)alloc((size_t)50176 * 4);
  float* SP = (float*)alloc((size_t)256 * 256 * 4);
  float* SN = (float*)alloc((size_t)256 * 256 * 4);
  float* val = (float*)alloc((size_t)256 * 256 * 4);

  hipMemsetAsync(out, 0, 2 * sizeof(float), stream);

  prep_all_k<<<38656, 256, 0, stream>>>(ea, Wf1, Wf2, Wc1, Wc2, eab, wf1b,
                                        wf2b, wb1, wb2, (unsigned int*)x1b);
  evpad_k<<<dim3(256, 6), 256, 0, stream>>>(ev, evb);

  // conv1: relu, cell rows k-major (one image per block-x, N=512, K=9*384)
  convtap6_k<6, 0><<<dim3(256, 4), 256, 0, stream>>>(evb, wb1, x1b);
  // fc1 / fc2
  gemm1_k<2048, 512, 0><<<dim3(2, 4), 256, 0, stream>>>(eab, wf1b, hb, nullptr);
  gemm1_k<512, 512, 2><<<dim3(2, 4), 256, 0, stream>>>(hb, wf2b, fa, nullptr);
  // conv2: compact bf16 out (one image per block-x, N=512, K=9*512)
  convtap6_k<8, 1><<<dim3(256, 4), 256, 0, stream>>>(x1b, wb2, fv);

  pool_k<<<256, 512, 0, stream>>>(fv, msk, indnb, ivpb, Pi, rn);
  fanorm_k<<<256, 512, 0, stream>>>(fa, fab, Qj);

  // Sij[(i,p), j] = rn[i,p] * <fv[i,p,:], indn[j,:]>  (M=50176, N=256, K=512)
  gemm1_k<512, 256, 3><<<dim3(392, 2), 256, 0, stream>>>(fv, indnb, Sij, rn);
  gemm_xv_k<<<dim3(2, 2, 2), 256, 0, stream>>>(ivpb, fab, indnb, Xm, Vm);

  spsn_k<<<dim3(256, 4), 256, 0, stream>>>(Sij, SP, SN);
  loss12_k<<<512, 256, 0, stream>>>(SP, SN, out);
  distcomb_k<<<256, 256, 0, stream>>>(Pi, Qj, Xm, Vm, val, out);
  loss4_k<<<256, 256, 0, stream>>>(val, out);
}

// Round 8
// 759.267 us; speedup vs baseline: 1.1068x; 1.0298x over previous
//
#include <hip/hip_runtime.h>
#include <stdint.h>

// ---------------------------------------------------------------------------
// B=256, H=W=14, HW=196, TS=0.03, TC=0.07, TP_K=19, TN_K=98
// Conv inputs: padded 16x16 cell grid per image (1-cell zero halo):
// cell = b*256 + (h+1)*16 + (w+1). Conv 3x3 = 9 cell-row shifts d=dh*16+dw.
// convtap6_k: block = ONE image (M padded 196->224 rows) x 128 N. The A
// window per kc is EXACTLY the image's 256 cell rows (36.9 KB) — covers all
// 9 taps incl. halo with no clamping, no cross-image span. acc 7x4/wave.
// M-tiling: each 16x16 MFMA tile = a 2x8 PIXEL BLOCK of the padded grid
// (tq -> dh=tq>>3, dw=tq&7; mi -> h-pair 1+2*mi; wm -> w-half) so the A-read
// bank-start residue 4*((tq&7)+quad) is uniform per quarter-wave, all taps.
// B PATH (R7-measured schedule, kept): weights in per-wave REGISTERS,
// fragment-packed; b0 (h0 frags) double-buffered one step ahead; b1 (h1)
// loaded at step top, used after the h0 cluster; af0+af1 read before the
// h0 cluster. R7 result: 250->221.5us, MfmaUtil 48.5->54.5%.
// R8 CHANGE — compile-time induction: inner 9-tap loop fully unrolled so
// (a) A tap offsets are CONSTANTS folded into ds_read offset immediates
//     (pab re-biased by -17 rows so all tap offsets >=0: OFF(t,h) =
//     (17+(dh-1)*16+(dw-1))*144 + h*64, max 5008 B);
// (b) t/9 div-mod chains vanish; B address = per-kc base + const-t term.
// R7 PMC showed VALUBusy 24.5% ~= 450 VALU cyc/wave/step of addressing —
// that work competes with MFMA issue at 2 waves/SIMD. Also s_setprio(1)
// around MFMA clusters (waves have load/compute role diversity here).
// Block mapping: DEFAULT (img=bx, n0=by*128): same-img blocks on same XCD.
// Grid 256x4 at 2 blocks/CU -> exactly 4 slots/CU, no tail quantization.
// NOTE: workspace regions are reused; size each by the MAX of its occupants.
// ---------------------------------------------------------------------------

typedef __attribute__((ext_vector_type(8))) short bf16x8;
typedef __attribute__((ext_vector_type(4))) float f32x4;

__device__ __forceinline__ unsigned short f2bf(float x) {
  unsigned u = __float_as_uint(x);
  unsigned r = u + 0x7FFFu + ((u >> 16) & 1u);  // RNE, no NaNs here
  return (unsigned short)(r >> 16);
}
__device__ __forceinline__ float bf2f(unsigned short h) {
  return __uint_as_float(((unsigned)h) << 16);
}

typedef const __attribute__((address_space(1))) void* gptr1_t;
typedef __attribute__((address_space(3))) void* lptr3_t;
__device__ __forceinline__ void gload_lds16(const void* g, void* l) {
  __builtin_amdgcn_global_load_lds((gptr1_t)g, (lptr3_t)l, 16, 0, 0);
}

__device__ __forceinline__ float waveSum(float v) {
#pragma unroll
  for (int m = 1; m < 64; m <<= 1) v += __shfl_xor(v, m, 64);
  return v;
}
__device__ __forceinline__ float waveMax(float v) {
#pragma unroll
  for (int m = 1; m < 64; m <<= 1) v = fmaxf(v, __shfl_xor(v, m, 64));
  return v;
}
template <int NW>
__device__ __forceinline__ float blockSum(float v) {
  __shared__ float sh[NW];
  v = waveSum(v);
  int wv = threadIdx.x >> 6, ln = threadIdx.x & 63;
  if (ln == 0) sh[wv] = v;
  __syncthreads();
  float r = 0.f;
#pragma unroll
  for (int w = 0; w < NW; ++w) r += sh[w];
  __syncthreads();
  return r;
}
template <int NW>
__device__ __forceinline__ float blockMax(float v) {
  __shared__ float sh[NW];
  v = waveMax(v);
  int wv = threadIdx.x >> 6, ln = threadIdx.x & 63;
  if (ln == 0) sh[wv] = v;
  __syncthreads();
  float r = -3.4e38f;
#pragma unroll
  for (int w = 0; w < NW; ++w) r = fmaxf(r, sh[w]);
  __syncthreads();
  return r;
}

#define RA 65536  // rows per k-slice of conv input buffers

// ---------------------------------------------------------------------------
// convtap6_k: one image per block-x. C[p,n] = sum_t sum_k A[cell(p)+d_t,k]B[t,n,k]
// 256 thr, 4 waves (wm in {0,1}: w-half, wn in {0,1}: 64 cols), acc 7x4 of
// 16x16x32 bf16 MFMA. A: [kc][RA][72] shorts (LDS window 256x72 = 36.9 KB).
// B: fragment-packed [t][kc][g(32)][h(2)][lane(64)][8] shorts, reg-loaded.
// EPI 0: relu -> x1b (cell rows, k-major slices). EPI 1: bf16 -> fv compact.
// ---------------------------------------------------------------------------
template <int KC, int EPI>
__global__ __launch_bounds__(256, 2) void convtap6_k(
    const unsigned short* __restrict__ A, const unsigned short* __restrict__ Bw,
    unsigned short* __restrict__ C) {
  __shared__ __align__(16) short Ah[256 * 72];
  const int tid = threadIdx.x;
  const int wave = tid >> 6, lane = tid & 63;
  const int wm = wave >> 1, wn = wave & 1;
  const int quad = lane >> 4, tq = lane & 15;
  const int img = blockIdx.x, n0 = blockIdx.y * 128;

  // A BYTE-base per mi, biased -17 rows so every tap offset immediate >= 0:
  // read addr = pab[mi] + OFF(t,h), OFF = (17+(dh-1)*16+(dw-1))*144 + h*64.
  int pab[7];
  {
    const int dh = tq >> 3;
    int wq = wm * 8 + (tq & 7);          // w' in 0..15
    if (wq == 0) wq = 8;                 // dead col -> mirrored valid col
    else if (wq == 15) wq = 7;
#pragma unroll
    for (int mi = 0; mi < 7; ++mi) {
      int pr = (1 + 2 * mi + dh) * 16 + wq;   // 17..239
      pab[mi] = (pr - 17) * 144 + quad * 16;  // bytes
    }
  }
  // B fragment base (shorts): (t*KC+kc)*32768 + g*1024 + h*512 + lane*8
  const int gb = (n0 >> 4) + wn * 4;

  const char* Ab = (const char*)A;
  const char* AhB = (const char*)Ah;
  const int l16 = lane * 16;

  f32x4 acc[7][4];
#pragma unroll
  for (int mi = 0; mi < 7; ++mi)
#pragma unroll
    for (int ni = 0; ni < 4; ++ni) {
      f32x4 z = {0.f, 0.f, 0.f, 0.f};
      acc[mi][ni] = z;
    }

  auto stageA = [&](int kc) {
    size_t s0 = ((size_t)kc * RA + img * 256) * 144;
#pragma unroll
    for (int i = 0; i < 9; ++i) {
      int c = wave + i * 4;  // 36 chunks of 1024 B
      gload_lds16(Ab + s0 + (size_t)c * 1024 + l16, (char*)Ah + c * 1024);
    }
  };

  stageA(0);
  bf16x8 b0[4], b1[4];
  {  // h0 frags of (kc=0,t=0): overlaps A staging + barrier
    const size_t w0 = ((size_t)gb * 128 + lane) * 8;
#pragma unroll
    for (int ni = 0; ni < 4; ++ni)
      b0[ni] = *(const bf16x8*)&Bw[w0 + (size_t)ni * 1024];
  }
  __syncthreads();

#pragma unroll 1
  for (int kc = 0; kc < KC; ++kc) {
    const size_t bk = ((size_t)kc * 4096 + gb * 128 + lane) * 8;  // shorts
#pragma unroll
    for (int t = 0; t < 9; ++t) {
      const size_t tof = (size_t)t * KC * 32768;  // compile-time
      // h1 frags of this step: used after the h0 cluster (~650 cyc)
#pragma unroll
      for (int ni = 0; ni < 4; ++ni)
        b1[ni] = *(const bf16x8*)&Bw[bk + tof + (size_t)ni * 1024 + 512];
      // prefetch next step's h0 frags (~full step of cover)
      bf16x8 b0n[4];
      const bool last = (t == 8) && (kc == KC - 1);
      if (!last) {
        const size_t nbase =
            (t < 8) ? bk + (size_t)(t + 1) * KC * 32768 : bk + 32768;
#pragma unroll
        for (int ni = 0; ni < 4; ++ni)
          b0n[ni] = *(const bf16x8*)&Bw[nbase + (size_t)ni * 1024];
      }
      // A fragments: base reg + CONSTANT offset (folds into ds_read imm)
      const int OFF = (17 + (t / 3 - 1) * 16 + (t % 3 - 1)) * 144;
      bf16x8 af0[7], af1[7];
#pragma unroll
      for (int mi = 0; mi < 7; ++mi)
        af0[mi] = *(const bf16x8*)(AhB + pab[mi] + OFF);
#pragma unroll
      for (int mi = 0; mi < 7; ++mi)
        af1[mi] = *(const bf16x8*)(AhB + pab[mi] + OFF + 64);
      __builtin_amdgcn_s_setprio(1);
#pragma unroll
      for (int mi = 0; mi < 7; ++mi)
#pragma unroll
        for (int ni = 0; ni < 4; ++ni)
          acc[mi][ni] = __builtin_amdgcn_mfma_f32_16x16x32_bf16(
              af0[mi], b0[ni], acc[mi][ni], 0, 0, 0);
#pragma unroll
      for (int mi = 0; mi < 7; ++mi)
#pragma unroll
        for (int ni = 0; ni < 4; ++ni)
          acc[mi][ni] = __builtin_amdgcn_mfma_f32_16x16x32_bf16(
              af1[mi], b1[ni], acc[mi][ni], 0, 0, 0);
      __builtin_amdgcn_s_setprio(0);
      if (!last) {
#pragma unroll
        for (int ni = 0; ni < 4; ++ni) b0[ni] = b0n[ni];  // SSA rename, free
      }
    }
    if (kc + 1 < KC) {  // A window restage at kc boundary
      __syncthreads();
      stageA(kc + 1);
      __syncthreads();
    }
  }

#pragma unroll
  for (int mi = 0; mi < 7; ++mi) {
#pragma unroll
    for (int r = 0; r < 4; ++r) {
      int idx = quad * 4 + r;            // M-row within tile, 0..15
      int wv = wm * 8 + (idx & 7);       // w' in 0..15
      if (wv == 0 || wv == 15) continue;  // dead column (halo)
      int hh = 1 + 2 * mi + (idx >> 3);  // h' in 1..14
      if (EPI == 0) {
        int cell = img * 256 + hh * 16 + wv;
        int slice = (n0 >> 6) + wn;
        size_t ob = ((size_t)slice * RA + cell) * 72 + tq;
#pragma unroll
        for (int ni = 0; ni < 4; ++ni)
          C[ob + ni * 16] = f2bf(fmaxf(acc[mi][ni][r], 0.f));
      } else {
        int p = (hh - 1) * 14 + (wv - 1);
        size_t ob = (size_t)(img * 196 + p) * 512 + n0 + wn * 64 + tq;
#pragma unroll
        for (int ni = 0; ni < 4; ++ni)
          C[ob + ni * 16] = f2bf(acc[mi][ni][r]);
      }
    }
  }
}

// ---------------------------------------------------------------------------
// gemm1_k: C[m,n] = sum_k A[m,k]*B[n,k]; 128x128 tile, 4 waves, BK=64,
// XOR-swizzled LDS. EPI: 0 relu->bf16, 2 f32, 3 f32 * rs[m] (row scale).
// ---------------------------------------------------------------------------
template <int K, int NLD, int EPI>
__global__ __launch_bounds__(256, 2) void gemm1_k(
    const unsigned short* __restrict__ A, const unsigned short* __restrict__ Bw,
    void* __restrict__ C, const float* __restrict__ rs) {
  __shared__ short As[128 * 64];
  __shared__ short Bs[128 * 64];
  const int tid = threadIdx.x;
  const int wave = tid >> 6, lane = tid & 63;
  const int m0 = blockIdx.x * 128, n0 = blockIdx.y * 128;
  const int rr8 = lane >> 3, seg = lane & 7, gseg = seg ^ rr8;
  const int wm = wave >> 1, wn = wave & 1;
  const int quad = lane >> 4, tq = lane & 15;

  size_t asrc[4], bsrc[4];
#pragma unroll
  for (int i8 = 0; i8 < 4; ++i8) {
    int rloc = wave * 32 + i8 * 8 + rr8;
    asrc[i8] = (size_t)(m0 + rloc) * K + gseg * 8;
    bsrc[i8] = (size_t)(n0 + rloc) * K + gseg * 8;
  }

  f32x4 acc[4][4];
#pragma unroll
  for (int mi = 0; mi < 4; ++mi)
#pragma unroll
    for (int ni = 0; ni < 4; ++ni) {
      f32x4 z = {0.f, 0.f, 0.f, 0.f};
      acc[mi][ni] = z;
    }

#pragma unroll 1
  for (int kc2 = 0; kc2 < K / 64; ++kc2) {
    int kb = kc2 * 64;
    __syncthreads();
#pragma unroll
    for (int i8 = 0; i8 < 4; ++i8) {
      gload_lds16(A + asrc[i8] + kb, &As[(wave * 32 + i8 * 8) * 64]);
      gload_lds16(Bw + bsrc[i8] + kb, &Bs[(wave * 32 + i8 * 8) * 64]);
    }
    __syncthreads();
#pragma unroll
    for (int h = 0; h < 2; ++h) {
      bf16x8 af[4], bfr[4];
#pragma unroll
      for (int mi = 0; mi < 4; ++mi) {
        int row = wm * 64 + mi * 16 + tq;
        af[mi] = *(const bf16x8*)&As[row * 64 +
                                     ((((h << 2) | quad) ^ (row & 7)) << 3)];
      }
#pragma unroll
      for (int ni = 0; ni < 4; ++ni) {
        int row = wn * 64 + ni * 16 + tq;
        bfr[ni] = *(const bf16x8*)&Bs[row * 64 +
                                      ((((h << 2) | quad) ^ (row & 7)) << 3)];
      }
#pragma unroll
      for (int mi = 0; mi < 4; ++mi)
#pragma unroll
        for (int ni = 0; ni < 4; ++ni)
          acc[mi][ni] = __builtin_amdgcn_mfma_f32_16x16x32_bf16(
              af[mi], bfr[ni], acc[mi][ni], 0, 0, 0);
    }
  }

#pragma unroll
  for (int mi = 0; mi < 4; ++mi) {
#pragma unroll
    for (int r = 0; r < 4; ++r) {
      int m = m0 + wm * 64 + mi * 16 + quad * 4 + r;
      float sc = (EPI == 3) ? rs[m] : 1.f;
      size_t obase = (size_t)m * NLD + n0 + wn * 64 + tq;
#pragma unroll
      for (int ni = 0; ni < 4; ++ni) {
        float v = acc[mi][ni][r];
        size_t idx = obase + ni * 16;
        if (EPI == 0)
          ((unsigned short*)C)[idx] = f2bf(fmaxf(v, 0.f));
        else if (EPI == 2)
          ((float*)C)[idx] = v;
        else
          ((float*)C)[idx] = v * sc;
      }
    }
  }
}

// Xm = (iv+eps).fa^T and Vm = indn.indn^T in one dispatch (blockIdx.z picks)
__global__ __launch_bounds__(256, 2) void gemm_xv_k(
    const unsigned short* __restrict__ ivpb, const unsigned short* __restrict__ fab,
    const unsigned short* __restrict__ indnb, float* __restrict__ Xm,
    float* __restrict__ Vm) {
  const unsigned short* A = blockIdx.z ? indnb : ivpb;
  const unsigned short* Bw = blockIdx.z ? indnb : fab;
  float* C = blockIdx.z ? Vm : Xm;
  __shared__ short As[128 * 64];
  __shared__ short Bs[128 * 64];
  const int tid = threadIdx.x;
  const int wave = tid >> 6, lane = tid & 63;
  const int m0 = blockIdx.x * 128, n0 = blockIdx.y * 128;
  const int rr8 = lane >> 3, seg = lane & 7, gseg = seg ^ rr8;
  const int wm = wave >> 1, wn = wave & 1;
  const int quad = lane >> 4, tq = lane & 15;
  size_t asrc[4], bsrc[4];
#pragma unroll
  for (int i8 = 0; i8 < 4; ++i8) {
    int rloc = wave * 32 + i8 * 8 + rr8;
    asrc[i8] = (size_t)(m0 + rloc) * 512 + gseg * 8;
    bsrc[i8] = (size_t)(n0 + rloc) * 512 + gseg * 8;
  }
  f32x4 acc[4][4];
#pragma unroll
  for (int mi = 0; mi < 4; ++mi)
#pragma unroll
    for (int ni = 0; ni < 4; ++ni) {
      f32x4 z = {0.f, 0.f, 0.f, 0.f};
      acc[mi][ni] = z;
    }
#pragma unroll 1
  for (int kc2 = 0; kc2 < 8; ++kc2) {
    int kb = kc2 * 64;
    __syncthreads();
#pragma unroll
    for (int i8 = 0; i8 < 4; ++i8) {
      gload_lds16(A + asrc[i8] + kb, &As[(wave * 32 + i8 * 8) * 64]);
      gload_lds16(Bw + bsrc[i8] + kb, &Bs[(wave * 32 + i8 * 8) * 64]);
    }
    __syncthreads();
#pragma unroll
    for (int h = 0; h < 2; ++h) {
      bf16x8 af[4], bfr[4];
#pragma unroll
      for (int mi = 0; mi < 4; ++mi) {
        int row = wm * 64 + mi * 16 + tq;
        af[mi] = *(const bf16x8*)&As[row * 64 +
                                     ((((h << 2) | quad) ^ (row & 7)) << 3)];
      }
#pragma unroll
      for (int ni = 0; ni < 4; ++ni) {
        int row = wn * 64 + ni * 16 + tq;
        bfr[ni] = *(const bf16x8*)&Bs[row * 64 +
                                      ((((h << 2) | quad) ^ (row & 7)) << 3)];
      }
#pragma unroll
      for (int mi = 0; mi < 4; ++mi)
#pragma unroll
        for (int ni = 0; ni < 4; ++ni)
          acc[mi][ni] = __builtin_amdgcn_mfma_f32_16x16x32_bf16(
              af[mi], bfr[ni], acc[mi][ni], 0, 0, 0);
    }
  }
#pragma unroll
  for (int mi = 0; mi < 4; ++mi)
#pragma unroll
    for (int r = 0; r < 4; ++r) {
      int m = m0 + wm * 64 + mi * 16 + quad * 4 + r;
      size_t obase = (size_t)m * 256 + n0 + wn * 64 + tq;
#pragma unroll
      for (int ni = 0; ni < 4; ++ni) C[obase + ni * 16] = acc[mi][ni][r];
    }
}

// --------------------------- prep (fused) ----------------------------------
// ranges: ea/Wf1/Wf2 casts | wb1 build | wb2 build | x1b halo zeroing
// wb layout (fragment-packed): flat index j =
//   (((t*KC+kc)*32 + g)*2 + h)*512 + quad*128 + tq*8 + jj
// value = Wc[n = g*16+tq][cin = kc*64 + h*32 + quad*8 + jj][tap t]
// -> writes are perfectly linear; the conv kernel reads 1KB coalesced spans.
__global__ void prep_all_k(const float* __restrict__ ea,
                           const float* __restrict__ Wf1,
                           const float* __restrict__ Wf2,
                           const float* __restrict__ Wc1,
                           const float* __restrict__ Wc2,
                           unsigned short* __restrict__ eab,
                           unsigned short* __restrict__ wf1b,
                           unsigned short* __restrict__ wf2b,
                           unsigned short* __restrict__ wb1,
                           unsigned short* __restrict__ wb2,
                           unsigned int* __restrict__ x1u) {
  int i = blockIdx.x * 256 + threadIdx.x;
  if (i < 524288) {
    eab[i] = f2bf(ea[i]);
  } else if (i < 1572864) {
    int j = i - 524288;
    wf1b[j] = f2bf(Wf1[j]);
  } else if (i < 1835008) {
    int j = i - 1572864;
    wf2b[j] = f2bf(Wf2[j]);
  } else if (i < 3604480) {
    int j = i - 1835008;  // wb1: 9*6*32768 fragment-packed <- Wc1[n][384][3][3]
    int t = j / (6 * 32768), r = j - t * (6 * 32768);
    int kc = r / 32768, r2 = r - kc * 32768;
    int g = r2 >> 10, h = (r2 >> 9) & 1, quad = (r2 >> 7) & 3;
    int tq = (r2 >> 3) & 15, jj = r2 & 7;
    int n = g * 16 + tq, cin = kc * 64 + h * 32 + quad * 8 + jj;
    wb1[j] = f2bf(Wc1[(n * 384 + cin) * 9 + t]);
  } else if (i < 5963776) {
    int j = i - 3604480;  // wb2: 9*8*32768 fragment-packed <- Wc2[n][512][3][3]
    int t = j / (8 * 32768), r = j - t * (8 * 32768);
    int kc = r / 32768, r2 = r - kc * 32768;
    int g = r2 >> 10, h = (r2 >> 9) & 1, quad = (r2 >> 7) & 3;
    int tq = (r2 >> 3) & 15, jj = r2 & 7;
    int n = g * 16 + tq, cin = kc * 64 + h * 32 + quad * 8 + jj;
    wb2[j] = f2bf(Wc2[(n * 512 + cin) * 9 + t]);
  } else {
    int j = i - 5963776;  // 15360 halo rows x 8 slices x 32 uints
    int hr = j >> 8, u = j & 255;
    int slice = u >> 5, uu = u & 31;
    int b = hr / 60, c = hr - b * 60;
    int cell;
    if (c < 16) cell = c;
    else if (c < 32) cell = 240 + (c - 16);
    else if (c < 46) cell = (c - 31) * 16;
    else cell = (c - 45) * 16 + 15;
    x1u[((size_t)slice * RA + b * 256 + cell) * 36 + uu] = 0u;
  }
}

// ev (256,384,14,14) fp32 -> evb [kc6][RA][72] bf16 (halo cells zero)
__global__ __launch_bounds__(256) void evpad_k(const float* __restrict__ ev,
                                               unsigned short* __restrict__ out) {
  int b = blockIdx.x, ct = blockIdx.y;  // channel tile: c0 = ct*64
  __shared__ float tile[64][197];
  int tid = threadIdx.x;
  const float* src = ev + ((size_t)b * 384 + ct * 64) * 196;
#pragma unroll 1
  for (int it = 0; it < 49; ++it) {
    int idx = it * 256 + tid;
    int c = idx / 196, p = idx - c * 196;
    tile[c][p] = src[idx];
  }
  __syncthreads();
  unsigned short* dst = out + ((size_t)ct * RA + b * 256) * 72;
#pragma unroll 1
  for (int it = 0; it < 64; ++it) {
    int idx = it * 256 + tid;
    int cell = idx >> 6, c = idx & 63;
    int h = (cell >> 4) - 1, w = (cell & 15) - 1;
    float v = ((unsigned)h < 14u && (unsigned)w < 14u) ? tile[c][h * 14 + w]
                                                       : 0.f;
    dst[(size_t)cell * 72 + c] = f2bf(v);
  }
}

// --------------------------- pooling / norms -------------------------------

// fused: masked mean pool + per-pixel inverse norm (rn) + ind normalization
__global__ __launch_bounds__(512) void pool_k(
    const unsigned short* __restrict__ fv, const int* __restrict__ masks,
    unsigned short* __restrict__ indnb, unsigned short* __restrict__ ivpb,
    float* __restrict__ Pi, float* __restrict__ rn) {
  int b = blockIdx.x;
  int w = threadIdx.x >> 6, lane = threadIdx.x & 63;
  __shared__ float red[8][512];
  __shared__ float msh[8];
  float acc[8] = {0.f, 0.f, 0.f, 0.f, 0.f, 0.f, 0.f, 0.f};
  float msum = 0.f;
  for (int p = w; p < 196; p += 8) {
    float m = (float)masks[b * 196 + p];
    msum += m;
    uint4 d = *(const uint4*)(fv + (size_t)(b * 196 + p) * 512 + lane * 8);
    const unsigned short* hp = (const unsigned short*)&d;
    float ss = 0.f;
#pragma unroll
    for (int k = 0; k < 8; ++k) {
      float x = bf2f(hp[k]);
      ss += x * x;
      acc[k] += m * x;
    }
    ss = waveSum(ss);
    if (lane == 0) rn[b * 196 + p] = 1.f / fmaxf(sqrtf(ss), 1e-12f);
  }
#pragma unroll
  for (int k = 0; k < 8; ++k) red[w][lane * 8 + k] = acc[k];
  if (lane == 0) msh[w] = msum;
  __syncthreads();
  int tid = threadIdx.x;
  float s = 0.f, mtot = 0.f;
#pragma unroll
  for (int ww = 0; ww < 8; ++ww) {
    s += red[ww][tid];
    mtot += msh[ww];
  }
  float v = s / mtot;  // indv[b, tid]
  float ss2 = blockSum<8>(v * v);
  float sc = 1.f / fmaxf(sqrtf(ss2), 1e-12f);
  indnb[b * 512 + tid] = f2bf(v * sc);
  float ve = v + 1e-6f;
  ivpb[b * 512 + tid] = f2bf(ve);
  float p2 = blockSum<8>(ve * ve);
  if (tid == 0) Pi[b] = p2;
}

// fa fp32 -> bf16 + Qj = ||fa_j||^2
__global__ __launch_bounds__(512) void fanorm_k(const float* __restrict__ fa,
                                                unsigned short* __restrict__ fab,
                                                float* __restrict__ Qj) {
  int b = blockIdx.x, tid = threadIdx.x;
  float v = fa[b * 512 + tid];
  fab[b * 512 + tid] = f2bf(v);
  float q = blockSum<8>(v * v);
  if (tid == 0) Qj[b] = q;
}

// ------------------------------ SP / SN ------------------------------------

__device__ __forceinline__ float radix_kth(unsigned k0, unsigned k1, unsigned k2,
                                           unsigned k3, int k) {
  unsigned prefix = 0;
  int kk = k;
#pragma unroll 1
  for (int bit = 31; bit >= 14; --bit) {  // 18 steps; thr err ~2^-9 rel, ok
    unsigned thi = (prefix >> bit) | 1u;
    int c = __popcll(__ballot((k0 >> bit) == thi)) +
            __popcll(__ballot((k1 >> bit) == thi)) +
            __popcll(__ballot((k2 >> bit) == thi)) +
            __popcll(__ballot((k3 >> bit) == thi));
    if (kk <= c)
      prefix |= (1u << bit);
    else
      kk -= c;
  }
  unsigned u = (prefix & 0x80000000u) ? (prefix ^ 0x80000000u) : ~prefix;
  return __uint_as_float(u);
}
__device__ __forceinline__ unsigned sortkey(float x) {
  unsigned u = __float_as_uint(x);
  return u ^ (((int)u >> 31) | 0x80000000u);
}

__global__ __launch_bounds__(256) void spsn_k(const float* __restrict__ Sij,
                                              float* __restrict__ SP,
                                              float* __restrict__ SN) {
  int i = blockIdx.x, jg = blockIdx.y;
  int tid = threadIdx.x, wave = tid >> 6, lane = tid & 63;
  __shared__ float tile[196 * 65];
#pragma unroll 1
  for (int it = 0; it < 49; ++it) {
    int lin = it * 256 + tid;
    int p = lin >> 6, j = lin & 63;
    tile[p * 65 + j] = Sij[(size_t)(i * 196 + p) * 256 + jg * 64 + j];
  }
  __syncthreads();
#pragma unroll 1
  for (int jj = 0; jj < 16; ++jj) {
    int j = jj * 4 + wave;
    float v0 = tile[lane * 65 + j];
    float v1 = tile[(lane + 64) * 65 + j];
    float v2 = tile[(lane + 128) * 65 + j];
    bool val3 = lane < 4;
    float v3 = val3 ? tile[(lane + 192) * 65 + j] : 0.f;
    unsigned k0 = sortkey(v0), k1 = sortkey(v1), k2 = sortkey(v2);
    unsigned k3 = val3 ? sortkey(v3) : 0u;
    float thrP = radix_kth(k0, k1, k2, k3, 19);
    float thrN = radix_kth(k0, k1, k2, k3, 99);
    float spn = 0.f, spd = 0.f, snn = 0.f, snd = 0.f;
    const float invTS = 1.f / 0.03f;
#pragma unroll
    for (int q = 0; q < 4; ++q) {
      float v = (q == 0) ? v0 : (q == 1) ? v1 : (q == 2) ? v2 : v3;
      bool ok = (q < 3) || val3;
      if (ok) {
        float mp = 1.f / (1.f + __expf((thrP - v) * invTS));
        float mn = 1.f / (1.f + __expf((v - thrN) * invTS));
        spn += v * mp;
        spd += mp;
        snn += v * mn;
        snd += mn;
      }
    }
    spn = waveSum(spn); spd = waveSum(spd);
    snn = waveSum(snn); snd = waveSum(snd);
    if (lane == 0) {
      SP[i * 256 + jg * 64 + j] = spn / spd;
      SN[i * 256 + jg * 64 + j] = snn / snd;
    }
  }
}

__global__ __launch_bounds__(256) void loss12_k(const float* __restrict__ SP,
                                                const float* __restrict__ SN,
                                                float* __restrict__ out) {
  int r = blockIdx.x;
  int i = r & 255;
  bool col = r >= 256;
  int tid = threadIdx.x;
  const float invTC = 1.f / 0.07f;
  float a = (col ? SP[tid * 256 + i] : SP[i * 256 + tid]) * invTC;
  float b = (col ? SN[tid * 256 + i] : SN[i * 256 + tid]) * invTC;
  float mx = blockMax<4>(fmaxf(a, b));
  float se = blockSum<4>(__expf(a - mx) + __expf(b - mx));
  float lse = mx + __logf(se);
  if (tid == 0) {
    float diag = SP[i * 256 + i] * invTC;
    atomicAdd(out, -(diag - lse) * (1.f / 512.f));
  }
}

__global__ __launch_bounds__(256) void distcomb_k(
    const float* __restrict__ Pi, const float* __restrict__ Qj,
    const float* __restrict__ X, const float* __restrict__ V,
    float* __restrict__ val, float* __restrict__ out) {
  int i = blockIdx.x, j = threadIdx.x;
  float d = Pi[i] - 2.f * X[i * 256 + j] + Qj[j];
  float w = (i == j) ? 1.f : -V[i * 256 + j];
  float x = d * w;
  val[i * 256 + j] = x;
  __shared__ float diag_sh;
  if (j == i) diag_sh = x;
  float tot = blockSum<4>(x);
  if (j == 0) {
    float rs = diag_sh - (tot - diag_sh) * (1.f / 255.f);
    atomicAdd(out + 1, fmaxf(rs + 0.6f, 0.f) * (1.f / 512.f));
  }
}

__global__ __launch_bounds__(256) void loss4_k(const float* __restrict__ val,
                                               float* __restrict__ out) {
  int j = blockIdx.x, i = threadIdx.x;
  float x = val[i * 256 + j];
  __shared__ float diag_sh;
  if (i == j) diag_sh = x;
  float tot = blockSum<4>(x);
  if (i == 0) {
    float cs = diag_sh - (tot - diag_sh) * (1.f / 255.f);
    atomicAdd(out + 1, fmaxf(cs + 0.6f, 0.f) * (1.f / 512.f));
  }
}

// ---------------------------------------------------------------------------

extern "C" void kernel_launch(void* const* d_in, const int* in_sizes, int n_in,
                              void* d_out, int out_size, void* d_ws,
                              size_t ws_size, hipStream_t stream) {
  (void)in_sizes; (void)n_in; (void)out_size; (void)ws_size;
  const float* ev = (const float*)d_in[0];
  const float* ea = (const float*)d_in[1];
  const int* msk = (const int*)d_in[2];
  const float* Wf1 = (const float*)d_in[3];
  const float* Wf2 = (const float*)d_in[4];
  const float* Wc1 = (const float*)d_in[5];
  const float* Wc2 = (const float*)d_in[6];
  float* out = (float*)d_out;
  char* ws = (char*)d_ws;

  size_t off = 0;
  auto alloc = [&](size_t bytes) {
    void* p = ws + off;
    off = (off + bytes + 255) & ~(size_t)255;
    return p;
  };
  // Region 1: max(evb 6*RA*144 = 56.6 MB ; fv 50176*512*2 = 51.4 MB)
  unsigned short* evb = (unsigned short*)alloc((size_t)6 * RA * 144);
  unsigned short* fv = evb;  // reused after conv2
  // Region 2: max(x1b 8*RA*144 = 75.5 MB ; Sij 50176*256*4 = 51.4 MB)
  unsigned short* x1b = (unsigned short*)alloc((size_t)8 * RA * 144);
  float* Sij = (float*)x1b;  // reused after conv2
  unsigned short* wb1 = (unsigned short*)alloc((size_t)9 * 6 * 32768 * 2);
  unsigned short* wb2 = (unsigned short*)alloc((size_t)9 * 8 * 32768 * 2);
  unsigned short* eab = (unsigned short*)alloc((size_t)256 * 2048 * 2);
  unsigned short* wf1b = (unsigned short*)alloc((size_t)512 * 2048 * 2);
  unsigned short* wf2b = (unsigned short*)alloc((size_t)512 * 512 * 2);
  unsigned short* hb = (unsigned short*)alloc((size_t)256 * 512 * 2);
  float* fa = (float*)alloc((size_t)256 * 512 * 4);
  unsigned short* indnb = (unsigned short*)alloc((size_t)256 * 512 * 2);
  unsigned short* ivpb = (unsigned short*)alloc((size_t)256 * 512 * 2);
  unsigned short* fab = (unsigned short*)alloc((size_t)256 * 512 * 2);
  float* Pi = (float*)alloc(256 * 4);
  float* Qj = (float*)alloc(256 * 4);
  float* Xm = (float*)alloc((size_t)256 * 256 * 4);
  float* Vm = (float*)alloc((size_t)256 * 256 * 4);
  float* rn = (float*)alloc((size_t)50176 * 4);
  float* SP = (float*)alloc((size_t)256 * 256 * 4);
  float* SN = (float*)alloc((size_t)256 * 256 * 4);
  float* val = (float*)alloc((size_t)256 * 256 * 4);

  hipMemsetAsync(out, 0, 2 * sizeof(float), stream);

  prep_all_k<<<38656, 256, 0, stream>>>(ea, Wf1, Wf2, Wc1, Wc2, eab, wf1b,
                                        wf2b, wb1, wb2, (unsigned int*)x1b);
  evpad_k<<<dim3(256, 6), 256, 0, stream>>>(ev, evb);

  // conv1: relu, cell rows k-major (one image per block-x, N=512, K=9*384)
  convtap6_k<6, 0><<<dim3(256, 4), 256, 0, stream>>>(evb, wb1, x1b);
  // fc1 / fc2
  gemm1_k<2048, 512, 0><<<dim3(2, 4), 256, 0, stream>>>(eab, wf1b, hb, nullptr);
  gemm1_k<512, 512, 2><<<dim3(2, 4), 256, 0, stream>>>(hb, wf2b, fa, nullptr);
  // conv2: compact bf16 out (one image per block-x, N=512, K=9*512)
  convtap6_k<8, 1><<<dim3(256, 4), 256, 0, stream>>>(x1b, wb2, fv);

  pool_k<<<256, 512, 0, stream>>>(fv, msk, indnb, ivpb, Pi, rn);
  fanorm_k<<<256, 512, 0, stream>>>(fa, fab, Qj);

  // Sij[(i,p), j] = rn[i,p] * <fv[i,p,:], indn[j,:]>  (M=50176, N=256, K=512)
  gemm1_k<512, 256, 3><<<dim3(392, 2), 256, 0, stream>>>(fv, indnb, Sij, rn);
  gemm_xv_k<<<dim3(2, 2, 2), 256, 0, stream>>>(ivpb, fab, indnb, Xm, Vm);

  spsn_k<<<dim3(256, 4), 256, 0, stream>>>(Sij, SP, SN);
  loss12_k<<<512, 256, 0, stream>>>(SP, SN, out);
  distcomb_k<<<256, 256, 0, stream>>>(Pi, Qj, Xm, Vm, val, out);
  loss4_k<<<256, 256, 0, stream>>>(val, out);
}